// Round 1
// 242.558 us; speedup vs baseline: 1.0253x; 1.0253x over previous
//
#include <hip/hip_runtime.h>
#include <hip/hip_bf16.h>

// SelfAttention: B=4, S=2048, D=1024, fp32 in/out.
// Round 9: qkvt ported to the 8-phase 256x256 counted-vmcnt template
// (T2+T3+T4+T5). scores/pv/prep unchanged from R8.
//  - qkvt_gemm8: 256x256 tile, BK=64, 8 waves (512thr), 128KiB LDS dbuf,
//    16x16x32 f16 MFMA, chunk-XOR swizzle (proven 0-conflict in scores),
//    vmcnt(4) at phases 4/8 only. Grid 384 (QK 32x8 + VT 4x32), 1 blk/CU.
//  - scores: R5's 128x128 16x16x32 gemm (53.4us measured).
//  - pv: gemm128 + lpart->linv LDS preamble + XCD-friendly grid.
//  - prep: cast x + 3 weight transposes.
// 4 launches: prep, qkvt8, scores, pv.

typedef _Float16 half_t;
typedef _Float16 half8 __attribute__((ext_vector_type(8)));
typedef _Float16 half4v __attribute__((ext_vector_type(4)));
typedef float f32x4 __attribute__((ext_vector_type(4)));

__device__ __forceinline__ void load16_to_lds(const half_t* g, half_t* l) {
  __builtin_amdgcn_global_load_lds(
      (const __attribute__((address_space(1))) void*)g,
      (__attribute__((address_space(3))) void*)l, 16, 0, 0);
}

// ---------------- qkvt: 8-phase 256x256 tile, 16x16x32 f16 -------------------
// 1D grid of 384 blocks, 512 threads (8 waves, 2M x 4N; wave tile 128x64).
// Blocks [0,256): qk[8192,2048] = x @ [Wq|Wk]^T  (32 m-tiles x 8 n-tiles)
// Blocks [256,384): vtg[1024,8192] = Wv^T @ x^T  (4 m-tiles x 32 n-tiles)
// lda = ldb = 1024 (K=1024) in both roles.
// LDS layout: tile row r (64 halfs), chunk slot p holds global chunk p^(r&7)
// -> staged with pre-swizzled global source + linear lds dest (rule 21);
//    ds_read pos = ((kk*4+lq)^(lm&7))*8, 0-conflict (measured in scores).
// Phase schedule (iteration = K-tiles 2i[buf0], 2i+1[buf1]; 2 gload/phase):
//   P1: rd a0-3,b0-1(buf0); stage A-lo(2i+1)->buf1   | mfma Q(m03,n01)
//   P2: rd b2-3(buf0);      stage A-hi(2i+1)->buf1   | mfma Q(m03,n23)
//   P3: rd a4-7(buf0);      stage B-lo(2i+2)->buf0   | mfma Q(m47,n01)
//   P4:                     stage B-hi(2i+2)->buf0   | mfma Q(m47,n23); vmcnt(4)
//   P5-P8: same on buf1, staging A(2i+2)->buf0, B(2i+3)->buf1; vmcnt(4) at P8.
// Every stage targets a region whose readers completed >=1 trailing barrier
// earlier; vmcnt(4) leaves exactly the 2 newest phases' loads in flight.
__global__ __launch_bounds__(512, 2) void qkvt_gemm8(
    const half_t* __restrict__ xh, const half_t* __restrict__ wt,
    half_t* __restrict__ qk, half_t* __restrict__ vtg) {
  __shared__ __align__(16) half_t As[2][256 * 64];
  __shared__ __align__(16) half_t Bs[2][256 * 64];

  int b = blockIdx.x;
  const half_t* A; const half_t* Bm; half_t* C;
  int ldc, m0, n0;
  if (b < 256) {  // QK: M=8192, N=2048
    A = xh; Bm = wt; C = qk; ldc = 2048;
    m0 = (b >> 3) * 256; n0 = (b & 7) * 256;
  } else {        // VT: M=1024, N=8192
    b -= 256;
    A = wt + (size_t)2 * 1024 * 1024; Bm = xh; C = vtg; ldc = 8192;
    m0 = (b >> 5) * 256; n0 = (b & 31) * 256;
  }

  const int t     = threadIdx.x;
  const int lane  = t & 63;
  const int wave  = t >> 6;
  const int wr128 = (wave >> 2) * 128;  // wave m-base within tile
  const int wc64  = (wave & 3) * 64;    // wave n-base within tile
  const int lm    = lane & 15;
  const int lq    = lane >> 4;
  const int pos0  = (lq ^ (lm & 7)) * 8;
  const int pos1  = ((4 + lq) ^ (lm & 7)) * 8;
  const int t8    = t * 8;

  const int trow = t >> 3;                    // 0..63
  const int tchk = (t & 7) ^ (trow & 7);      // pre-swizzled global chunk
  const half_t* gA0 = A  + (size_t)(m0 + trow) * 1024 + tchk * 8;
  const half_t* gB0 = Bm + (size_t)(n0 + trow) * 1024 + tchk * 8;

  f32x4 acc[8][4] = {};
  half8 va[4][2], vb0[2][2], vb1[2][2];

#define ST_A(buf, h, kt) do {                                                  \
    load16_to_lds(gA0 + (size_t)((h)*128) * 1024 + (size_t)(kt) * 64,          \
                  &As[buf][(h)*128*64] + t8);                                  \
    load16_to_lds(gA0 + (size_t)((h)*128+64) * 1024 + (size_t)(kt) * 64,       \
                  &As[buf][((h)*128+64)*64] + t8);                             \
  } while (0)
#define ST_B(buf, h, kt) do {                                                  \
    load16_to_lds(gB0 + (size_t)((h)*128) * 1024 + (size_t)(kt) * 64,          \
                  &Bs[buf][(h)*128*64] + t8);                                  \
    load16_to_lds(gB0 + (size_t)((h)*128+64) * 1024 + (size_t)(kt) * 64,       \
                  &Bs[buf][((h)*128+64)*64] + t8);                             \
  } while (0)
#define RD_A(buf, mh) do {                                                     \
    _Pragma("unroll") for (int m = 0; m < 4; ++m) {                            \
      const int ar = wr128 + (mh)*64 + m * 16 + lm;                            \
      va[m][0] = *(const half8*)&As[buf][ar * 64 + pos0];                      \
      va[m][1] = *(const half8*)&As[buf][ar * 64 + pos1];                      \
    } } while (0)
#define RD_B(buf, nh, vb) do {                                                 \
    _Pragma("unroll") for (int n = 0; n < 2; ++n) {                            \
      const int br = wc64 + (nh)*32 + n * 16 + lm;                             \
      vb[n][0] = *(const half8*)&Bs[buf][br * 64 + pos0];                      \
      vb[n][1] = *(const half8*)&Bs[buf][br * 64 + pos1];                      \
    } } while (0)
#define MF_Q(mh, nh, vb) do {                                                  \
    _Pragma("unroll") for (int kk = 0; kk < 2; ++kk)                           \
    _Pragma("unroll") for (int m = 0; m < 4; ++m)                              \
    _Pragma("unroll") for (int n = 0; n < 2; ++n)                              \
      acc[(mh)*4+m][(nh)*2+n] = __builtin_amdgcn_mfma_f32_16x16x32_f16(        \
          va[m][kk], vb[n][kk], acc[(mh)*4+m][(nh)*2+n], 0, 0, 0);             \
  } while (0)
#define LGKM0 asm volatile("s_waitcnt lgkmcnt(0)" ::: "memory")
#define BAR   __builtin_amdgcn_s_barrier()
#define PRIO1 __builtin_amdgcn_s_setprio(1)
#define PRIO0 __builtin_amdgcn_s_setprio(0)

  // Prologue: A(0),B(0)->buf0; B(1)->buf1. vmcnt(4) leaves only B(1) in flight.
  ST_A(0, 0, 0); ST_A(0, 1, 0);
  ST_B(0, 0, 0); ST_B(0, 1, 0);
  ST_B(1, 0, 1); ST_B(1, 1, 1);
  asm volatile("s_waitcnt vmcnt(4)" ::: "memory");
  BAR;

#pragma unroll 1
  for (int i = 0; i < 8; ++i) {
    const int st1 = (2 * i + 1 < 15) ? 2 * i + 1 : 15;  // A -> buf1
    const int st2 = (2 * i + 2 < 15) ? 2 * i + 2 : 15;  // B,A -> buf0
    const int st3 = (2 * i + 3 < 15) ? 2 * i + 3 : 15;  // B -> buf1
    // ---- P1
    RD_A(0, 0); RD_B(0, 0, vb0);
    ST_A(1, 0, st1);
    asm volatile("s_waitcnt lgkmcnt(8)" ::: "memory");
    BAR; LGKM0;
    PRIO1; MF_Q(0, 0, vb0); PRIO0;
    BAR;
    // ---- P2
    RD_B(0, 1, vb1);
    ST_A(1, 1, st1);
    BAR; LGKM0;
    PRIO1; MF_Q(0, 1, vb1); PRIO0;
    BAR;
    // ---- P3
    RD_A(0, 1);
    ST_B(0, 0, st2);
    BAR; LGKM0;
    PRIO1; MF_Q(1, 0, vb0); PRIO0;
    BAR;
    // ---- P4
    ST_B(0, 1, st2);
    BAR; LGKM0;
    PRIO1; MF_Q(1, 1, vb1); PRIO0;
    asm volatile("s_waitcnt vmcnt(4)" ::: "memory");
    BAR;
    // ---- P5
    RD_A(1, 0); RD_B(1, 0, vb0);
    ST_A(0, 0, st2);
    asm volatile("s_waitcnt lgkmcnt(8)" ::: "memory");
    BAR; LGKM0;
    PRIO1; MF_Q(0, 0, vb0); PRIO0;
    BAR;
    // ---- P6
    RD_B(1, 1, vb1);
    ST_A(0, 1, st2);
    BAR; LGKM0;
    PRIO1; MF_Q(0, 1, vb1); PRIO0;
    BAR;
    // ---- P7
    RD_A(1, 1);
    ST_B(1, 0, st3);
    BAR; LGKM0;
    PRIO1; MF_Q(1, 0, vb0); PRIO0;
    BAR;
    // ---- P8
    ST_B(1, 1, st3);
    BAR; LGKM0;
    PRIO1; MF_Q(1, 1, vb1); PRIO0;
    asm volatile("s_waitcnt vmcnt(4)" ::: "memory");
    BAR;
  }

  // 16x16 C/D: col=lane&15, row=(lane>>4)*4+reg  [m89/m91]
#pragma unroll
  for (int m = 0; m < 8; ++m)
#pragma unroll
    for (int n = 0; n < 4; ++n) {
      const int col = n0 + wc64 + n * 16 + lm;
#pragma unroll
      for (int r = 0; r < 4; ++r) {
        const int row = m0 + wr128 + m * 16 + lq * 4 + r;
        C[(size_t)row * ldc + col] = (half_t)acc[m][n][r];
      }
    }
#undef ST_A
#undef ST_B
#undef RD_A
#undef RD_B
#undef MF_Q
#undef LGKM0
#undef BAR
#undef PRIO1
#undef PRIO0
}

// ------------- scores: P = exp(qk^T/32 - 8), 128x128 tile, 16x16x32 ----------
// Grid (16 n-tiles, 16 m-tiles, 4 b) — R5's measured-53us shape. Epilogue
// writes non-atomic partials lpart[(z*2048+row)*32 + nx*2 + (wave&1)].
// LDS XOR swizzle: conflict-free (R3/R5 measured 0).
__global__ __launch_bounds__(256) void scores_gemm(
    const half_t* __restrict__ qk, half_t* __restrict__ sc,
    float* __restrict__ lpart) {
  __shared__ __align__(16) half_t As[128 * 64];
  __shared__ __align__(16) half_t Bs[128 * 64];

  const int z  = blockIdx.z;
  const int m0 = blockIdx.y * 128;
  const int n0 = blockIdx.x * 128;
  const half_t* A  = qk + (size_t)z * 2048 * 2048;  // q rows (ld 2048)
  const half_t* Bm = A + 1024;                      // k rows
  half_t* C = sc + (size_t)z * 2048 * 2048;
  constexpr int lda = 2048, ldb = 2048, ldc = 2048, K = 1024;

  const int t    = threadIdx.x;
  const int wave = t >> 6;
  const int lane = t & 63;
  const int wm   = (wave >> 1) * 64;
  const int wn   = (wave & 1) * 64;
  const int lm   = lane & 15;
  const int lq   = lane >> 4;
  const int lswz = lm & 7;

  const int trow = t >> 3;
  const int tchk = (t & 7) ^ (trow & 7);

  const half_t* gA0 = A  + (size_t)(m0 + trow) * lda + tchk * 8;
  const half_t* gB0 = Bm + (size_t)(n0 + trow) * ldb + tchk * 8;
  const size_t stepA = (size_t)32 * lda;
  const size_t stepB = (size_t)32 * ldb;

  half_t* lA0 = &As[t * 8];
  half_t* lB0 = &Bs[t * 8];

  f32x4 acc[4][4] = {};

  for (int k0 = 0; k0 < K; k0 += 64) {
    __syncthreads();
#pragma unroll
    for (int n = 0; n < 4; ++n) {
      load16_to_lds(gA0 + n * stepA + k0, lA0 + n * 2048);
      load16_to_lds(gB0 + n * stepB + k0, lB0 + n * 2048);
    }
    __syncthreads();

#pragma unroll
    for (int kk = 0; kk < 2; ++kk) {
      const int pos = ((kk * 4 + lq) ^ lswz) * 8;
      half8 a[4], bf[4];
#pragma unroll
      for (int i = 0; i < 4; ++i)
        a[i] = *(const half8*)&As[(wm + i * 16 + lm) * 64 + pos];
#pragma unroll
      for (int j = 0; j < 4; ++j)
        bf[j] = *(const half8*)&Bs[(wn + j * 16 + lm) * 64 + pos];
#pragma unroll
      for (int i = 0; i < 4; ++i)
#pragma unroll
        for (int j = 0; j < 4; ++j)
          acc[i][j] = __builtin_amdgcn_mfma_f32_16x16x32_f16(a[i], bf[j], acc[i][j], 0, 0, 0);
    }
  }

  const float scale = 1.0f / 32.0f;
#pragma unroll
  for (int i = 0; i < 4; ++i)
#pragma unroll
    for (int r = 0; r < 4; ++r) {
      const int row = m0 + wm + i * 16 + lq * 4 + r;
      float s = 0.f;
#pragma unroll
      for (int j = 0; j < 4; ++j) {
        const int col = n0 + wn + j * 16 + lm;
        float v = __expf(acc[i][j][r] * scale - 8.0f);
        s += v;
        C[(size_t)row * ldc + col] = (half_t)v;
      }
      // reduce across the 16-lane quad group; one store per (row, block, half)
      s += __shfl_xor(s, 1); s += __shfl_xor(s, 2);
      s += __shfl_xor(s, 4); s += __shfl_xor(s, 8);
      if (lm == 0)
        lpart[((size_t)z * 2048 + row) * 32 + blockIdx.x * 2 + (wave & 1)] = s;
    }
}

// --------------- pv: out = (P @ V) / l, 128x128 tile, 16x16x32 ---------------
// Grid (16 q-tiles, 8 d-tiles, 4 b): same-q blocks 16 apart -> same XCD
// (P row-block stays L2-resident across its 8 d-blocks).
__global__ __launch_bounds__(256) void pv_gemm(
    const half_t* __restrict__ sc, const half_t* __restrict__ vtg,
    float* __restrict__ out, const float* __restrict__ lpart) {
  __shared__ __align__(16) half_t As[128 * 64];
  __shared__ __align__(16) half_t Bs[128 * 64];
  __shared__ float linv[128];

  const int z  = blockIdx.z;
  const int m0 = blockIdx.x * 128;
  const int n0 = blockIdx.y * 128;
  const half_t* A  = sc  + (size_t)z * 2048 * 2048;
  const half_t* Bm = vtg + (size_t)z * 2048;
  float* C = out + (size_t)z * 2048 * 1024;
  constexpr int lda = 2048, ldb = 8192, ldc = 1024, K = 2048;

  const int t    = threadIdx.x;
  const int wave = t >> 6;
  const int lane = t & 63;
  const int wm   = (wave >> 1) * 64;
  const int wn   = (wave & 1) * 64;
  const int lm   = lane & 15;
  const int lq   = lane >> 4;
  const int lswz = lm & 7;

  // Reduce 32 per-row partials to 1/l (covered by the loop's first barrier)
  if (t < 128) {
    const float4* lp = (const float4*)&lpart[((size_t)z * 2048 + m0 + t) * 32];
    float s = 0.f;
#pragma unroll
    for (int p = 0; p < 8; ++p) {
      float4 v = lp[p];
      s += v.x + v.y + v.z + v.w;
    }
    linv[t] = 1.0f / s;
  }

  const int trow = t >> 3;
  const int tchk = (t & 7) ^ (trow & 7);

  const half_t* gA0 = A  + (size_t)(m0 + trow) * lda + tchk * 8;
  const half_t* gB0 = Bm + (size_t)(n0 + trow) * ldb + tchk * 8;
  const size_t stepA = (size_t)32 * lda;
  const size_t stepB = (size_t)32 * ldb;

  half_t* lA0 = &As[t * 8];
  half_t* lB0 = &Bs[t * 8];

  f32x4 acc[4][4] = {};

  for (int k0 = 0; k0 < K; k0 += 64) {
    __syncthreads();
#pragma unroll
    for (int n = 0; n < 4; ++n) {
      load16_to_lds(gA0 + n * stepA + k0, lA0 + n * 2048);
      load16_to_lds(gB0 + n * stepB + k0, lB0 + n * 2048);
    }
    __syncthreads();

#pragma unroll
    for (int kk = 0; kk < 2; ++kk) {
      const int pos = ((kk * 4 + lq) ^ lswz) * 8;
      half8 a[4], bf[4];
#pragma unroll
      for (int i = 0; i < 4; ++i)
        a[i] = *(const half8*)&As[(wm + i * 16 + lm) * 64 + pos];
#pragma unroll
      for (int j = 0; j < 4; ++j)
        bf[j] = *(const half8*)&Bs[(wn + j * 16 + lm) * 64 + pos];
#pragma unroll
      for (int i = 0; i < 4; ++i)
#pragma unroll
        for (int j = 0; j < 4; ++j)
          acc[i][j] = __builtin_amdgcn_mfma_f32_16x16x32_f16(a[i], bf[j], acc[i][j], 0, 0, 0);
    }
  }

#pragma unroll
  for (int i = 0; i < 4; ++i)
#pragma unroll
    for (int r = 0; r < 4; ++r) {
      const int lrow = wm + i * 16 + lq * 4 + r;
      const float inv = linv[lrow];
      const int row = m0 + lrow;
#pragma unroll
      for (int j = 0; j < 4; ++j) {
        const int col = n0 + wn + j * 16 + lm;
        C[(size_t)row * ldc + col] = acc[i][j][r] * inv;
      }
    }
}

// --------------- prep: cast x + transpose weights (1 launch) -----------------
__global__ __launch_bounds__(256) void prep(
    const float* __restrict__ x, half_t* __restrict__ xh,
    const float* __restrict__ Wq, const float* __restrict__ Wk,
    const float* __restrict__ Wv, half_t* __restrict__ wt) {
  __shared__ half_t tile[32][33];
  const int b = blockIdx.x;
  const int t = threadIdx.x;
  if (b < 8192) {
    const int i = (b * 256 + t) * 4;
    const float4 v = *reinterpret_cast<const float4*>(x + i);
    half4v o;
    o.x = (half_t)v.x; o.y = (half_t)v.y; o.z = (half_t)v.z; o.w = (half_t)v.w;
    *reinterpret_cast<half4v*>(xh + i) = o;
  } else {
    int bb = b - 8192;
    const int w = bb >> 10; bb &= 1023;
    const float* in = (w == 0) ? Wq : (w == 1) ? Wk : Wv;
    half_t* o = wt + (size_t)w * 1024 * 1024;
    const int r0 = (bb >> 5) * 32, c0 = (bb & 31) * 32;
    const int tx = t & 31, ty = t >> 5;
#pragma unroll
    for (int i = 0; i < 32; i += 8)
      tile[ty + i][tx] = (half_t)in[(size_t)(r0 + ty + i) * 1024 + c0 + tx];
    __syncthreads();
#pragma unroll
    for (int i = 0; i < 32; i += 8)
      o[(size_t)(c0 + ty + i) * 1024 + r0 + tx] = tile[tx][ty + i];
  }
}

extern "C" void kernel_launch(void* const* d_in, const int* in_sizes, int n_in,
                              void* d_out, int out_size, void* d_ws, size_t ws_size,
                              hipStream_t stream) {
  constexpr int Bb = 4, S = 2048, D = 1024;
  constexpr size_t MS = (size_t)Bb * S;  // 8192 rows

  const float* x  = (const float*)d_in[0];
  const float* Wq = (const float*)d_in[1];
  const float* Wk = (const float*)d_in[2];
  const float* Wv = (const float*)d_in[3];
  float* out = (float*)d_out;

  // Workspace carve (~103 MB).
  char* p = (char*)d_ws;
  half_t* xh    = (half_t*)p; p += MS * D * 2;               // 16 MB
  half_t* wt    = (half_t*)p; p += (size_t)3 * D * D * 2;    // 6 MB  [Wq|Wk|Wv]^T
  half_t* qk    = (half_t*)p; p += MS * (size_t)(2 * D) * 2; // 32 MB [B*S, 2D]
  half_t* vtg   = (half_t*)p; p += (size_t)D * MS * 2;       // 16 MB [D, B*S]
  half_t* sc    = (half_t*)p; p += (size_t)Bb * S * S * 2;   // 32 MB P=exp(s-8)
  float*  lpart = (float*)p;  p += MS * 32 * 4;              // 1 MB partial sums

  prep<<<11264, 256, 0, stream>>>(x, xh, Wq, Wk, Wv, wt);
  qkvt_gemm8<<<384, 512, 0, stream>>>(xh, wt, qk, vtg);
  scores_gemm<<<dim3(16, 16, Bb), 256, 0, stream>>>(qk, sc, lpart);
  pv_gemm<<<dim3(16, 8, Bb), 256, 0, stream>>>(sc, vtg, out, lpart);
}

// Round 2
// 236.549 us; speedup vs baseline: 1.0513x; 1.0254x over previous
//
#include <hip/hip_runtime.h>
#include <hip/hip_bf16.h>

// SelfAttention: B=4, S=2048, D=1024, fp32 in/out.
// Round 10: T1 (XCD chunked swizzle) everywhere + scores ported to the
// verified 256x256 8-phase skeleton (perfect 256-block grid).
//  - qkvt_gemm8: R9 loop body verbatim; block->tile map now gives each XCD
//    4 contiguous m-tiles (QK) / n-tiles (VT): per-XCD L2 set 16.5->6 MB.
//  - scores_gemm8: 8-phase 256^2, grid 256 = exactly 1 round, XCD swizzle
//    (z=x>>1, 4 by-tiles per XCD). lpart slot = bx*4 + (wave&3) (32/row).
//  - pv: unchanged R8 gemm128 (lpart preamble sums all 32 slots; layout-agnostic).
//  - prep: unchanged.
// 4 launches: prep, qkvt8, scores8, pv.

typedef _Float16 half_t;
typedef _Float16 half8 __attribute__((ext_vector_type(8)));
typedef _Float16 half4v __attribute__((ext_vector_type(4)));
typedef float f32x4 __attribute__((ext_vector_type(4)));

__device__ __forceinline__ void load16_to_lds(const half_t* g, half_t* l) {
  __builtin_amdgcn_global_load_lds(
      (const __attribute__((address_space(1))) void*)g,
      (__attribute__((address_space(3))) void*)l, 16, 0, 0);
}

#define LGKM0 asm volatile("s_waitcnt lgkmcnt(0)" ::: "memory")
#define LGKM8 asm volatile("s_waitcnt lgkmcnt(8)" ::: "memory")
#define VM4   asm volatile("s_waitcnt vmcnt(4)" ::: "memory")
#define BAR   __builtin_amdgcn_s_barrier()
#define PRIO1 __builtin_amdgcn_s_setprio(1)
#define PRIO0 __builtin_amdgcn_s_setprio(0)

// ---------------- qkvt: 8-phase 256x256 tile, 16x16x32 f16 -------------------
// 1D grid of 384 blocks, 512 threads (8 waves, 2M x 4N; wave tile 128x64).
// Blocks [0,256): qk[8192,2048] = x @ [Wq|Wk]^T   XCD x owns m-tiles 4x..4x+3
// Blocks [256,384): vtg[1024,8192] = Wv^T @ x^T   XCD x owns n-tiles 4x..4x+3
// (XCD = blockIdx.x % 8; mapping bijective. Per-XCD L2 set: 6 MB / 4 MB.)
// LDS: tile row r, chunk slot p holds global chunk p^(r&7) (pre-swizzled
// global source + linear lds dest). ds_read pos = (c ^ (lm&7))*8: 0-conflict.
// Phases/vmcnt identical to R9 (race-safe: every stage's consumer is behind
// a vmcnt(4) that drains it; never vmcnt(0) in the loop).
__global__ __launch_bounds__(512, 2) void qkvt_gemm8(
    const half_t* __restrict__ xh, const half_t* __restrict__ wt,
    half_t* __restrict__ qk, half_t* __restrict__ vtg) {
  __shared__ __align__(16) half_t As[2][256 * 64];
  __shared__ __align__(16) half_t Bs[2][256 * 64];

  const int b = blockIdx.x;
  const half_t* A; const half_t* Bm; half_t* C;
  int ldc, m0, n0;
  if (b < 256) {  // QK: M=8192, N=2048
    const int x = b & 7, j = b >> 3;
    A = xh; Bm = wt; C = qk; ldc = 2048;
    m0 = (x * 4 + (j & 3)) * 256;   // 4 contiguous m-tiles per XCD
    n0 = (j >> 2) * 256;
  } else {        // VT: M=1024, N=8192
    const int idv = b - 256;
    const int x = idv & 7, j = idv >> 3;
    A = wt + (size_t)2 * 1024 * 1024; Bm = xh; C = vtg; ldc = 8192;
    m0 = (j >> 2) * 256;
    n0 = (x * 4 + (j & 3)) * 256;   // 4 contiguous n-tiles per XCD
  }

  const int t     = threadIdx.x;
  const int lane  = t & 63;
  const int wave  = t >> 6;
  const int wr128 = (wave >> 2) * 128;
  const int wc64  = (wave & 3) * 64;
  const int lm    = lane & 15;
  const int lq    = lane >> 4;
  const int pos0  = (lq ^ (lm & 7)) * 8;
  const int pos1  = ((4 + lq) ^ (lm & 7)) * 8;
  const int t8    = t * 8;

  const int trow = t >> 3;
  const int tchk = (t & 7) ^ (trow & 7);
  const half_t* gA0 = A  + (size_t)(m0 + trow) * 1024 + tchk * 8;
  const half_t* gB0 = Bm + (size_t)(n0 + trow) * 1024 + tchk * 8;

  f32x4 acc[8][4] = {};
  half8 va[4][2], vb0[2][2], vb1[2][2];

#define ST_A(buf, h, kt) do {                                                  \
    load16_to_lds(gA0 + (size_t)((h)*128) * 1024 + (size_t)(kt) * 64,          \
                  &As[buf][(h)*128*64] + t8);                                  \
    load16_to_lds(gA0 + (size_t)((h)*128+64) * 1024 + (size_t)(kt) * 64,       \
                  &As[buf][((h)*128+64)*64] + t8);                             \
  } while (0)
#define ST_B(buf, h, kt) do {                                                  \
    load16_to_lds(gB0 + (size_t)((h)*128) * 1024 + (size_t)(kt) * 64,          \
                  &Bs[buf][(h)*128*64] + t8);                                  \
    load16_to_lds(gB0 + (size_t)((h)*128+64) * 1024 + (size_t)(kt) * 64,       \
                  &Bs[buf][((h)*128+64)*64] + t8);                             \
  } while (0)
#define RD_A(buf, mh) do {                                                     \
    _Pragma("unroll") for (int m = 0; m < 4; ++m) {                            \
      const int ar = wr128 + (mh)*64 + m * 16 + lm;                            \
      va[m][0] = *(const half8*)&As[buf][ar * 64 + pos0];                      \
      va[m][1] = *(const half8*)&As[buf][ar * 64 + pos1];                      \
    } } while (0)
#define RD_B(buf, nh, vb) do {                                                 \
    _Pragma("unroll") for (int n = 0; n < 2; ++n) {                            \
      const int br = wc64 + (nh)*32 + n * 16 + lm;                             \
      vb[n][0] = *(const half8*)&Bs[buf][br * 64 + pos0];                      \
      vb[n][1] = *(const half8*)&Bs[buf][br * 64 + pos1];                      \
    } } while (0)
#define MF_Q(mh, nh, vb) do {                                                  \
    _Pragma("unroll") for (int kk = 0; kk < 2; ++kk)                           \
    _Pragma("unroll") for (int m = 0; m < 4; ++m)                              \
    _Pragma("unroll") for (int n = 0; n < 2; ++n)                              \
      acc[(mh)*4+m][(nh)*2+n] = __builtin_amdgcn_mfma_f32_16x16x32_f16(        \
          va[m][kk], vb[n][kk], acc[(mh)*4+m][(nh)*2+n], 0, 0, 0);             \
  } while (0)

  ST_A(0, 0, 0); ST_A(0, 1, 0);
  ST_B(0, 0, 0); ST_B(0, 1, 0);
  ST_B(1, 0, 1); ST_B(1, 1, 1);
  VM4;
  BAR;

#pragma unroll 1
  for (int i = 0; i < 8; ++i) {
    const int st1 = (2 * i + 1 < 15) ? 2 * i + 1 : 15;
    const int st2 = (2 * i + 2 < 15) ? 2 * i + 2 : 15;
    const int st3 = (2 * i + 3 < 15) ? 2 * i + 3 : 15;
    // ---- P1
    RD_A(0, 0); RD_B(0, 0, vb0);
    ST_A(1, 0, st1);
    LGKM8;
    BAR; LGKM0;
    PRIO1; MF_Q(0, 0, vb0); PRIO0;
    BAR;
    // ---- P2
    RD_B(0, 1, vb1);
    ST_A(1, 1, st1);
    BAR; LGKM0;
    PRIO1; MF_Q(0, 1, vb1); PRIO0;
    BAR;
    // ---- P3
    RD_A(0, 1);
    ST_B(0, 0, st2);
    BAR; LGKM0;
    PRIO1; MF_Q(1, 0, vb0); PRIO0;
    BAR;
    // ---- P4
    ST_B(0, 1, st2);
    BAR; LGKM0;
    PRIO1; MF_Q(1, 1, vb1); PRIO0;
    VM4;
    BAR;
    // ---- P5
    RD_A(1, 0); RD_B(1, 0, vb0);
    ST_A(0, 0, st2);
    LGKM8;
    BAR; LGKM0;
    PRIO1; MF_Q(0, 0, vb0); PRIO0;
    BAR;
    // ---- P6
    RD_B(1, 1, vb1);
    ST_A(0, 1, st2);
    BAR; LGKM0;
    PRIO1; MF_Q(0, 1, vb1); PRIO0;
    BAR;
    // ---- P7
    RD_A(1, 1);
    ST_B(1, 0, st3);
    BAR; LGKM0;
    PRIO1; MF_Q(1, 0, vb0); PRIO0;
    BAR;
    // ---- P8
    ST_B(1, 1, st3);
    BAR; LGKM0;
    PRIO1; MF_Q(1, 1, vb1); PRIO0;
    VM4;
    BAR;
  }

  // 16x16 C/D: col=lane&15, row=(lane>>4)*4+reg  [m89/m91]
#pragma unroll
  for (int m = 0; m < 8; ++m)
#pragma unroll
    for (int n = 0; n < 4; ++n) {
      const int col = n0 + wc64 + n * 16 + lm;
#pragma unroll
      for (int r = 0; r < 4; ++r) {
        const int row = m0 + wr128 + m * 16 + lq * 4 + r;
        C[(size_t)row * ldc + col] = (half_t)acc[m][n][r];
      }
    }
#undef ST_A
#undef ST_B
#undef RD_A
#undef RD_B
#undef MF_Q
}

// ------------- scores: P = exp(qk^T/32 - 8), 256x256 tile, 8-phase ----------
// 1D grid 256 blocks (exactly 1 round), 512 threads. XCD x: z=x>>1, by in
// {(x&1)*4..+3}, bx 0..7 (per-XCD set: A 2 MB + B 4 MB). Same verified
// 8-phase body as qkvt (strides 2048). Epilogue: exp(acc/32-8), per-row
// 16-lane reduce, lpart slot = bx*4 + (wave&3)  (32 partials/row, as before).
__global__ __launch_bounds__(512, 2) void scores_gemm8(
    const half_t* __restrict__ qk, half_t* __restrict__ sc,
    float* __restrict__ lpart) {
  __shared__ __align__(16) half_t As[2][256 * 64];
  __shared__ __align__(16) half_t Bs[2][256 * 64];

  const int id  = blockIdx.x;
  const int x   = id & 7, j = id >> 3;
  const int bx  = j & 7;
  const int z   = x >> 1;
  const int by  = (x & 1) * 4 + (j >> 3);
  const int m0  = by * 256;
  const int n0  = bx * 256;
  const half_t* A  = qk + (size_t)z * 2048 * 2048;  // q rows (ld 2048)
  const half_t* Bm = A + 1024;                      // k rows
  half_t* C = sc + (size_t)z * 2048 * 2048;

  const int t     = threadIdx.x;
  const int lane  = t & 63;
  const int wave  = t >> 6;
  const int wr128 = (wave >> 2) * 128;
  const int wc64  = (wave & 3) * 64;
  const int lm    = lane & 15;
  const int lq    = lane >> 4;
  const int pos0  = (lq ^ (lm & 7)) * 8;
  const int pos1  = ((4 + lq) ^ (lm & 7)) * 8;
  const int t8    = t * 8;

  const int trow = t >> 3;
  const int tchk = (t & 7) ^ (trow & 7);
  const half_t* gA0 = A  + (size_t)(m0 + trow) * 2048 + tchk * 8;
  const half_t* gB0 = Bm + (size_t)(n0 + trow) * 2048 + tchk * 8;

  f32x4 acc[8][4] = {};
  half8 va[4][2], vb0[2][2], vb1[2][2];

#define ST_A(buf, h, kt) do {                                                  \
    load16_to_lds(gA0 + (size_t)((h)*128) * 2048 + (size_t)(kt) * 64,          \
                  &As[buf][(h)*128*64] + t8);                                  \
    load16_to_lds(gA0 + (size_t)((h)*128+64) * 2048 + (size_t)(kt) * 64,       \
                  &As[buf][((h)*128+64)*64] + t8);                             \
  } while (0)
#define ST_B(buf, h, kt) do {                                                  \
    load16_to_lds(gB0 + (size_t)((h)*128) * 2048 + (size_t)(kt) * 64,          \
                  &Bs[buf][(h)*128*64] + t8);                                  \
    load16_to_lds(gB0 + (size_t)((h)*128+64) * 2048 + (size_t)(kt) * 64,       \
                  &Bs[buf][((h)*128+64)*64] + t8);                             \
  } while (0)
#define RD_A(buf, mh) do {                                                     \
    _Pragma("unroll") for (int m = 0; m < 4; ++m) {                            \
      const int ar = wr128 + (mh)*64 + m * 16 + lm;                            \
      va[m][0] = *(const half8*)&As[buf][ar * 64 + pos0];                      \
      va[m][1] = *(const half8*)&As[buf][ar * 64 + pos1];                      \
    } } while (0)
#define RD_B(buf, nh, vb) do {                                                 \
    _Pragma("unroll") for (int n = 0; n < 2; ++n) {                            \
      const int br = wc64 + (nh)*32 + n * 16 + lm;                             \
      vb[n][0] = *(const half8*)&Bs[buf][br * 64 + pos0];                      \
      vb[n][1] = *(const half8*)&Bs[buf][br * 64 + pos1];                      \
    } } while (0)
#define MF_Q(mh, nh, vb) do {                                                  \
    _Pragma("unroll") for (int kk = 0; kk < 2; ++kk)                           \
    _Pragma("unroll") for (int m = 0; m < 4; ++m)                              \
    _Pragma("unroll") for (int n = 0; n < 2; ++n)                              \
      acc[(mh)*4+m][(nh)*2+n] = __builtin_amdgcn_mfma_f32_16x16x32_f16(        \
          va[m][kk], vb[n][kk], acc[(mh)*4+m][(nh)*2+n], 0, 0, 0);             \
  } while (0)

  ST_A(0, 0, 0); ST_A(0, 1, 0);
  ST_B(0, 0, 0); ST_B(0, 1, 0);
  ST_B(1, 0, 1); ST_B(1, 1, 1);
  VM4;
  BAR;

#pragma unroll 1
  for (int i = 0; i < 8; ++i) {
    const int st1 = (2 * i + 1 < 15) ? 2 * i + 1 : 15;
    const int st2 = (2 * i + 2 < 15) ? 2 * i + 2 : 15;
    const int st3 = (2 * i + 3 < 15) ? 2 * i + 3 : 15;
    // ---- P1
    RD_A(0, 0); RD_B(0, 0, vb0);
    ST_A(1, 0, st1);
    LGKM8;
    BAR; LGKM0;
    PRIO1; MF_Q(0, 0, vb0); PRIO0;
    BAR;
    // ---- P2
    RD_B(0, 1, vb1);
    ST_A(1, 1, st1);
    BAR; LGKM0;
    PRIO1; MF_Q(0, 1, vb1); PRIO0;
    BAR;
    // ---- P3
    RD_A(0, 1);
    ST_B(0, 0, st2);
    BAR; LGKM0;
    PRIO1; MF_Q(1, 0, vb0); PRIO0;
    BAR;
    // ---- P4
    ST_B(0, 1, st2);
    BAR; LGKM0;
    PRIO1; MF_Q(1, 1, vb1); PRIO0;
    VM4;
    BAR;
    // ---- P5
    RD_A(1, 0); RD_B(1, 0, vb0);
    ST_A(0, 0, st2);
    LGKM8;
    BAR; LGKM0;
    PRIO1; MF_Q(0, 0, vb0); PRIO0;
    BAR;
    // ---- P6
    RD_B(1, 1, vb1);
    ST_A(0, 1, st2);
    BAR; LGKM0;
    PRIO1; MF_Q(0, 1, vb1); PRIO0;
    BAR;
    // ---- P7
    RD_A(1, 1);
    ST_B(1, 0, st3);
    BAR; LGKM0;
    PRIO1; MF_Q(1, 0, vb0); PRIO0;
    BAR;
    // ---- P8
    ST_B(1, 1, st3);
    BAR; LGKM0;
    PRIO1; MF_Q(1, 1, vb1); PRIO0;
    VM4;
    BAR;
  }

  const float scale = 1.0f / 32.0f;
#pragma unroll
  for (int m = 0; m < 8; ++m)
#pragma unroll
    for (int r = 0; r < 4; ++r) {
      const int row = m0 + wr128 + m * 16 + lq * 4 + r;
      float s = 0.f;
#pragma unroll
      for (int n = 0; n < 4; ++n) {
        const int col = n0 + wc64 + n * 16 + lm;
        float v = __expf(acc[m][n][r] * scale - 8.0f);
        s += v;
        C[(size_t)row * 2048 + col] = (half_t)v;
      }
      s += __shfl_xor(s, 1); s += __shfl_xor(s, 2);
      s += __shfl_xor(s, 4); s += __shfl_xor(s, 8);
      if (lm == 0)
        lpart[((size_t)z * 2048 + row) * 32 + bx * 4 + (wave & 3)] = s;
    }
#undef ST_A
#undef ST_B
#undef RD_A
#undef RD_B
#undef MF_Q
}

// --------------- pv: out = (P @ V) / l, 128x128 tile, 16x16x32 ---------------
// Grid (16 q-tiles, 8 d-tiles, 4 b): same-q blocks 16 apart -> same XCD
// (P row-block stays L2-resident across its 8 d-blocks).
__global__ __launch_bounds__(256) void pv_gemm(
    const half_t* __restrict__ sc, const half_t* __restrict__ vtg,
    float* __restrict__ out, const float* __restrict__ lpart) {
  __shared__ __align__(16) half_t As[128 * 64];
  __shared__ __align__(16) half_t Bs[128 * 64];
  __shared__ float linv[128];

  const int z  = blockIdx.z;
  const int m0 = blockIdx.x * 128;
  const int n0 = blockIdx.y * 128;
  const half_t* A  = sc  + (size_t)z * 2048 * 2048;
  const half_t* Bm = vtg + (size_t)z * 2048;
  float* C = out + (size_t)z * 2048 * 1024;
  constexpr int lda = 2048, ldb = 8192, ldc = 1024, K = 2048;

  const int t    = threadIdx.x;
  const int wave = t >> 6;
  const int lane = t & 63;
  const int wm   = (wave >> 1) * 64;
  const int wn   = (wave & 1) * 64;
  const int lm   = lane & 15;
  const int lq   = lane >> 4;
  const int lswz = lm & 7;

  // Reduce 32 per-row partials to 1/l (covered by the loop's first barrier)
  if (t < 128) {
    const float4* lp = (const float4*)&lpart[((size_t)z * 2048 + m0 + t) * 32];
    float s = 0.f;
#pragma unroll
    for (int p = 0; p < 8; ++p) {
      float4 v = lp[p];
      s += v.x + v.y + v.z + v.w;
    }
    linv[t] = 1.0f / s;
  }

  const int trow = t >> 3;
  const int tchk = (t & 7) ^ (trow & 7);

  const half_t* gA0 = A  + (size_t)(m0 + trow) * lda + tchk * 8;
  const half_t* gB0 = Bm + (size_t)(n0 + trow) * ldb + tchk * 8;
  const size_t stepA = (size_t)32 * lda;
  const size_t stepB = (size_t)32 * ldb;

  half_t* lA0 = &As[t * 8];
  half_t* lB0 = &Bs[t * 8];

  f32x4 acc[4][4] = {};

  for (int k0 = 0; k0 < K; k0 += 64) {
    __syncthreads();
#pragma unroll
    for (int n = 0; n < 4; ++n) {
      load16_to_lds(gA0 + n * stepA + k0, lA0 + n * 2048);
      load16_to_lds(gB0 + n * stepB + k0, lB0 + n * 2048);
    }
    __syncthreads();

#pragma unroll
    for (int kk = 0; kk < 2; ++kk) {
      const int pos = ((kk * 4 + lq) ^ lswz) * 8;
      half8 a[4], bf[4];
#pragma unroll
      for (int i = 0; i < 4; ++i)
        a[i] = *(const half8*)&As[(wm + i * 16 + lm) * 64 + pos];
#pragma unroll
      for (int j = 0; j < 4; ++j)
        bf[j] = *(const half8*)&Bs[(wn + j * 16 + lm) * 64 + pos];
#pragma unroll
      for (int i = 0; i < 4; ++i)
#pragma unroll
        for (int j = 0; j < 4; ++j)
          acc[i][j] = __builtin_amdgcn_mfma_f32_16x16x32_f16(a[i], bf[j], acc[i][j], 0, 0, 0);
    }
  }

#pragma unroll
  for (int i = 0; i < 4; ++i)
#pragma unroll
    for (int r = 0; r < 4; ++r) {
      const int lrow = wm + i * 16 + lq * 4 + r;
      const float inv = linv[lrow];
      const int row = m0 + lrow;
#pragma unroll
      for (int j = 0; j < 4; ++j) {
        const int col = n0 + wn + j * 16 + lm;
        C[(size_t)row * ldc + col] = acc[i][j][r] * inv;
      }
    }
}

// --------------- prep: cast x + transpose weights (1 launch) -----------------
__global__ __launch_bounds__(256) void prep(
    const float* __restrict__ x, half_t* __restrict__ xh,
    const float* __restrict__ Wq, const float* __restrict__ Wk,
    const float* __restrict__ Wv, half_t* __restrict__ wt) {
  __shared__ half_t tile[32][33];
  const int b = blockIdx.x;
  const int t = threadIdx.x;
  if (b < 8192) {
    const int i = (b * 256 + t) * 4;
    const float4 v = *reinterpret_cast<const float4*>(x + i);
    half4v o;
    o.x = (half_t)v.x; o.y = (half_t)v.y; o.z = (half_t)v.z; o.w = (half_t)v.w;
    *reinterpret_cast<half4v*>(xh + i) = o;
  } else {
    int bb = b - 8192;
    const int w = bb >> 10; bb &= 1023;
    const float* in = (w == 0) ? Wq : (w == 1) ? Wk : Wv;
    half_t* o = wt + (size_t)w * 1024 * 1024;
    const int r0 = (bb >> 5) * 32, c0 = (bb & 31) * 32;
    const int tx = t & 31, ty = t >> 5;
#pragma unroll
    for (int i = 0; i < 32; i += 8)
      tile[ty + i][tx] = (half_t)in[(size_t)(r0 + ty + i) * 1024 + c0 + tx];
    __syncthreads();
#pragma unroll
    for (int i = 0; i < 32; i += 8)
      o[(size_t)(c0 + ty + i) * 1024 + r0 + tx] = tile[tx][ty + i];
  }
}

extern "C" void kernel_launch(void* const* d_in, const int* in_sizes, int n_in,
                              void* d_out, int out_size, void* d_ws, size_t ws_size,
                              hipStream_t stream) {
  constexpr int Bb = 4, S = 2048, D = 1024;
  constexpr size_t MS = (size_t)Bb * S;  // 8192 rows

  const float* x  = (const float*)d_in[0];
  const float* Wq = (const float*)d_in[1];
  const float* Wk = (const float*)d_in[2];
  const float* Wv = (const float*)d_in[3];
  float* out = (float*)d_out;

  // Workspace carve (~103 MB).
  char* p = (char*)d_ws;
  half_t* xh    = (half_t*)p; p += MS * D * 2;               // 16 MB
  half_t* wt    = (half_t*)p; p += (size_t)3 * D * D * 2;    // 6 MB  [Wq|Wk|Wv]^T
  half_t* qk    = (half_t*)p; p += MS * (size_t)(2 * D) * 2; // 32 MB [B*S, 2D]
  half_t* vtg   = (half_t*)p; p += (size_t)D * MS * 2;       // 16 MB [D, B*S]
  half_t* sc    = (half_t*)p; p += (size_t)Bb * S * S * 2;   // 32 MB P=exp(s-8)
  float*  lpart = (float*)p;  p += MS * 32 * 4;              // 1 MB partial sums

  prep<<<11264, 256, 0, stream>>>(x, xh, Wq, Wk, Wv, wt);
  qkvt_gemm8<<<384, 512, 0, stream>>>(xh, wt, qk, vtg);
  scores_gemm8<<<256, 512, 0, stream>>>(qk, sc, lpart);
  pv_gemm<<<dim3(16, 8, Bb), 256, 0, stream>>>(sc, vtg, out, lpart);
}

// Round 4
// 223.558 us; speedup vs baseline: 1.1124x; 1.0581x over previous
//
#include <hip/hip_runtime.h>
#include <hip/hip_bf16.h>

// SelfAttention: B=4, S=2048, D=1024, fp32 in/out.
// Round 12 (= R11 resubmit; prior bench died to container infra, kernel
// re-audited: uniform barriers, counted-vmcnt windows safe, bounds OK).
// One 256-block qkvt launch; every block does 1 QK 256x256 tile (T) +
// 1 VT 128x256 half-tile (T/2) -> uniform 1.5T/CU (kills 1.5-round tail).
//  - QK body: R10's verified 8-phase loop verbatim (XCD chunked map).
//  - VT body: same 8-phase skeleton at 128x256 (8 waves x 64x64 wave-tile,
//    8 MFMA/phase, staging at P3/P4/P7/P8 with VM6; safety windows:
//    B(b0) after P2-bar, A(b0) after P3-bar, B(b1) after P6-bar, A(b1)
//    after P7-bar). vmcnt(0) between parts orders LDS reuse.
//  - scores_gemm8 / pv / prep: unchanged from R10.
// 4 launches: prep, qkvt8, scores8, pv.

typedef _Float16 half_t;
typedef _Float16 half8 __attribute__((ext_vector_type(8)));
typedef _Float16 half4v __attribute__((ext_vector_type(4)));
typedef float f32x4 __attribute__((ext_vector_type(4)));

__device__ __forceinline__ void load16_to_lds(const half_t* g, half_t* l) {
  __builtin_amdgcn_global_load_lds(
      (const __attribute__((address_space(1))) void*)g,
      (__attribute__((address_space(3))) void*)l, 16, 0, 0);
}

#define LGKM0 asm volatile("s_waitcnt lgkmcnt(0)" ::: "memory")
#define LGKM8 asm volatile("s_waitcnt lgkmcnt(8)" ::: "memory")
#define VM0   asm volatile("s_waitcnt vmcnt(0)" ::: "memory")
#define VM4   asm volatile("s_waitcnt vmcnt(4)" ::: "memory")
#define VM6   asm volatile("s_waitcnt vmcnt(6)" ::: "memory")
#define BAR   __builtin_amdgcn_s_barrier()
#define PRIO1 __builtin_amdgcn_s_setprio(1)
#define PRIO0 __builtin_amdgcn_s_setprio(0)

// --------- qkvt: QK 256x256 tile + VT 128x256 half-tile per block ----------
// Grid 256 x 512 threads. x = b&7 (XCD), j = b>>3.
// QK: qk[8192,2048] = x @ [Wq|Wk]^T; m0=(x*4+(j&3))*256, n0=(j>>2)*256.
// VT: vtg[1024,8192] = Wv^T @ x^T;  m0v=(j>>2)*128, n0v=(x*4+(j&3))*256.
__global__ __launch_bounds__(512, 2) void qkvt_gemm8(
    const half_t* __restrict__ xh, const half_t* __restrict__ wt,
    half_t* __restrict__ qk, half_t* __restrict__ vtg) {
  __shared__ __align__(16) half_t As[2][256 * 64];
  __shared__ __align__(16) half_t Bs[2][256 * 64];

  const int b = blockIdx.x;
  const int x = b & 7, j = b >> 3;
  const int m0 = (x * 4 + (j & 3)) * 256;
  const int n0 = (j >> 2) * 256;

  const int t     = threadIdx.x;
  const int lane  = t & 63;
  const int wave  = t >> 6;
  const int wr128 = (wave >> 2) * 128;
  const int wc64  = (wave & 3) * 64;
  const int lm    = lane & 15;
  const int lq    = lane >> 4;
  const int pos0  = (lq ^ (lm & 7)) * 8;
  const int pos1  = ((4 + lq) ^ (lm & 7)) * 8;
  const int t8    = t * 8;

  const int trow = t >> 3;
  const int tchk = (t & 7) ^ (trow & 7);
  const half_t* gA0 = xh + (size_t)(m0 + trow) * 1024 + tchk * 8;
  const half_t* gB0 = wt + (size_t)(n0 + trow) * 1024 + tchk * 8;

  f32x4 acc[8][4] = {};
  half8 va[4][2], vb0[2][2], vb1[2][2];

#define ST_A(buf, h, kt) do {                                                  \
    load16_to_lds(gA0 + (size_t)((h)*128) * 1024 + (size_t)(kt) * 64,          \
                  &As[buf][(h)*128*64] + t8);                                  \
    load16_to_lds(gA0 + (size_t)((h)*128+64) * 1024 + (size_t)(kt) * 64,       \
                  &As[buf][((h)*128+64)*64] + t8);                             \
  } while (0)
#define ST_B(buf, h, kt) do {                                                  \
    load16_to_lds(gB0 + (size_t)((h)*128) * 1024 + (size_t)(kt) * 64,          \
                  &Bs[buf][(h)*128*64] + t8);                                  \
    load16_to_lds(gB0 + (size_t)((h)*128+64) * 1024 + (size_t)(kt) * 64,       \
                  &Bs[buf][((h)*128+64)*64] + t8);                             \
  } while (0)
#define RD_A(buf, mh) do {                                                     \
    _Pragma("unroll") for (int m = 0; m < 4; ++m) {                            \
      const int ar = wr128 + (mh)*64 + m * 16 + lm;                            \
      va[m][0] = *(const half8*)&As[buf][ar * 64 + pos0];                      \
      va[m][1] = *(const half8*)&As[buf][ar * 64 + pos1];                      \
    } } while (0)
#define RD_B(buf, nh, vb) do {                                                 \
    _Pragma("unroll") for (int n = 0; n < 2; ++n) {                            \
      const int br = wc64 + (nh)*32 + n * 16 + lm;                             \
      vb[n][0] = *(const half8*)&Bs[buf][br * 64 + pos0];                      \
      vb[n][1] = *(const half8*)&Bs[buf][br * 64 + pos1];                      \
    } } while (0)
#define MF_Q(mh, nh, vb) do {                                                  \
    _Pragma("unroll") for (int kk = 0; kk < 2; ++kk)                           \
    _Pragma("unroll") for (int m = 0; m < 4; ++m)                              \
    _Pragma("unroll") for (int n = 0; n < 2; ++n)                              \
      acc[(mh)*4+m][(nh)*2+n] = __builtin_amdgcn_mfma_f32_16x16x32_f16(        \
          va[m][kk], vb[n][kk], acc[(mh)*4+m][(nh)*2+n], 0, 0, 0);             \
  } while (0)

  ST_A(0, 0, 0); ST_A(0, 1, 0);
  ST_B(0, 0, 0); ST_B(0, 1, 0);
  ST_B(1, 0, 1); ST_B(1, 1, 1);
  VM4;
  BAR;

#pragma unroll 1
  for (int i = 0; i < 8; ++i) {
    const int st1 = (2 * i + 1 < 15) ? 2 * i + 1 : 15;
    const int st2 = (2 * i + 2 < 15) ? 2 * i + 2 : 15;
    const int st3 = (2 * i + 3 < 15) ? 2 * i + 3 : 15;
    // ---- P1
    RD_A(0, 0); RD_B(0, 0, vb0);
    ST_A(1, 0, st1);
    LGKM8;
    BAR; LGKM0;
    PRIO1; MF_Q(0, 0, vb0); PRIO0;
    BAR;
    // ---- P2
    RD_B(0, 1, vb1);
    ST_A(1, 1, st1);
    BAR; LGKM0;
    PRIO1; MF_Q(0, 1, vb1); PRIO0;
    BAR;
    // ---- P3
    RD_A(0, 1);
    ST_B(0, 0, st2);
    BAR; LGKM0;
    PRIO1; MF_Q(1, 0, vb0); PRIO0;
    BAR;
    // ---- P4
    ST_B(0, 1, st2);
    BAR; LGKM0;
    PRIO1; MF_Q(1, 1, vb1); PRIO0;
    VM4;
    BAR;
    // ---- P5
    RD_A(1, 0); RD_B(1, 0, vb0);
    ST_A(0, 0, st2);
    LGKM8;
    BAR; LGKM0;
    PRIO1; MF_Q(0, 0, vb0); PRIO0;
    BAR;
    // ---- P6
    RD_B(1, 1, vb1);
    ST_A(0, 1, st2);
    BAR; LGKM0;
    PRIO1; MF_Q(0, 1, vb1); PRIO0;
    BAR;
    // ---- P7
    RD_A(1, 1);
    ST_B(1, 0, st3);
    BAR; LGKM0;
    PRIO1; MF_Q(1, 0, vb0); PRIO0;
    BAR;
    // ---- P8
    ST_B(1, 1, st3);
    BAR; LGKM0;
    PRIO1; MF_Q(1, 1, vb1); PRIO0;
    VM4;
    BAR;
  }

  // 16x16 C/D: col=lane&15, row=(lane>>4)*4+reg  [m89/m91]
#pragma unroll
  for (int m = 0; m < 8; ++m)
#pragma unroll
    for (int n = 0; n < 4; ++n) {
      const int col = n0 + wc64 + n * 16 + lm;
#pragma unroll
      for (int r = 0; r < 4; ++r) {
        const int row = m0 + wr128 + m * 16 + lq * 4 + r;
        qk[(size_t)row * 2048 + col] = (half_t)acc[m][n][r];
      }
    }
#undef ST_A
#undef ST_B
#undef RD_A
#undef RD_B
#undef MF_Q

  // ======================= VT half-tile: 128x256, K=1024 ====================
  const int m0v = (j >> 2) * 128;
  const int n0v = (x * 4 + (j & 3)) * 256;
  const int wmv = (wave >> 2) * 64;   // 2 M-waves
  const int wnv = (wave & 3) * 64;    // 4 N-waves

  const half_t* gA2 = wt + (size_t)2 * 1024 * 1024 +
                      (size_t)(m0v + trow) * 1024 + tchk * 8;
  const half_t* gB2 = xh + (size_t)(n0v + trow) * 1024 + tchk * 8;

  f32x4 acc2[4][4] = {};

#define ST_A2(buf, kt) do {                                                    \
    load16_to_lds(gA2 + (size_t)(kt) * 64, &As[buf][0] + t8);                  \
    load16_to_lds(gA2 + (size_t)64 * 1024 + (size_t)(kt) * 64,                 \
                  &As[buf][64*64] + t8);                                       \
  } while (0)
#define ST_B2(buf, h, kt) do {                                                 \
    load16_to_lds(gB2 + (size_t)((h)*128) * 1024 + (size_t)(kt) * 64,          \
                  &Bs[buf][(h)*128*64] + t8);                                  \
    load16_to_lds(gB2 + (size_t)((h)*128+64) * 1024 + (size_t)(kt) * 64,       \
                  &Bs[buf][((h)*128+64)*64] + t8);                             \
  } while (0)
#define RD_A2(buf, mh) do {                                                    \
    _Pragma("unroll") for (int m = 0; m < 2; ++m) {                            \
      const int ar = wmv + (mh)*32 + m * 16 + lm;                              \
      va[(mh)*2+m][0] = *(const half8*)&As[buf][ar * 64 + pos0];               \
      va[(mh)*2+m][1] = *(const half8*)&As[buf][ar * 64 + pos1];               \
    } } while (0)
#define RD_B2(buf, nh, vb) do {                                                \
    _Pragma("unroll") for (int n = 0; n < 2; ++n) {                            \
      const int br = wnv + (nh)*32 + n * 16 + lm;                              \
      vb[n][0] = *(const half8*)&Bs[buf][br * 64 + pos0];                      \
      vb[n][1] = *(const half8*)&Bs[buf][br * 64 + pos1];                      \
    } } while (0)
#define MF_V(mh, nh, vb) do {                                                  \
    _Pragma("unroll") for (int kk = 0; kk < 2; ++kk)                           \
    _Pragma("unroll") for (int m = 0; m < 2; ++m)                              \
    _Pragma("unroll") for (int n = 0; n < 2; ++n)                              \
      acc2[(mh)*2+m][(nh)*2+n] = __builtin_amdgcn_mfma_f32_16x16x32_f16(       \
          va[(mh)*2+m][kk], vb[n][kk], acc2[(mh)*2+m][(nh)*2+n], 0, 0, 0);     \
  } while (0)

  // Drain QK's in-flight staged loads + epilogue stores before LDS reuse.
  VM0;
  ST_B2(0, 0, 0); ST_B2(0, 1, 0); ST_A2(0, 0);   // b0 <- K-tile 0
  ST_B2(1, 0, 1); ST_B2(1, 1, 1); ST_A2(1, 1);   // b1 <- K-tile 1
  VM6;
  BAR;

#pragma unroll 1
  for (int i = 0; i < 8; ++i) {
    const int t2 = (2 * i + 2 < 15) ? 2 * i + 2 : 15;
    const int t3 = (2 * i + 3 < 15) ? 2 * i + 3 : 15;
    // ---- P1
    RD_A2(0, 0); RD_B2(0, 0, vb0);
    BAR; LGKM0;
    PRIO1; MF_V(0, 0, vb0); PRIO0;
    BAR;
    // ---- P2
    RD_B2(0, 1, vb1);
    BAR; LGKM0;
    PRIO1; MF_V(0, 1, vb1); PRIO0;
    BAR;
    // ---- P3  (B(b0) reads done after P2-bar)
    RD_A2(0, 1);
    ST_B2(0, 0, t2);
    BAR; LGKM0;
    PRIO1; MF_V(1, 0, vb0); PRIO0;
    BAR;
    // ---- P4  (A(b0) reads done after P3-bar)
    ST_B2(0, 1, t2); ST_A2(0, t2);
    BAR; LGKM0;
    PRIO1; MF_V(1, 1, vb1); PRIO0;
    VM6;              // drains the 6 b1 loads (issued prev P7/P8 or prologue)
    BAR;
    // ---- P5
    RD_A2(1, 0); RD_B2(1, 0, vb0);
    BAR; LGKM0;
    PRIO1; MF_V(0, 0, vb0); PRIO0;
    BAR;
    // ---- P6
    RD_B2(1, 1, vb1);
    BAR; LGKM0;
    PRIO1; MF_V(0, 1, vb1); PRIO0;
    BAR;
    // ---- P7  (B(b1) reads done after P6-bar)
    RD_A2(1, 1);
    ST_B2(1, 0, t3);
    BAR; LGKM0;
    PRIO1; MF_V(1, 0, vb0); PRIO0;
    BAR;
    // ---- P8  (A(b1) reads done after P7-bar)
    ST_B2(1, 1, t3); ST_A2(1, t3);
    BAR; LGKM0;
    PRIO1; MF_V(1, 1, vb1); PRIO0;
    VM6;              // drains the 6 b0 loads (issued P3/P4)
    BAR;
  }

#pragma unroll
  for (int m = 0; m < 4; ++m)
#pragma unroll
    for (int n = 0; n < 4; ++n) {
      const int col = n0v + wnv + n * 16 + lm;
#pragma unroll
      for (int r = 0; r < 4; ++r) {
        const int row = m0v + wmv + m * 16 + lq * 4 + r;
        vtg[(size_t)row * 8192 + col] = (half_t)acc2[m][n][r];
      }
    }
#undef ST_A2
#undef ST_B2
#undef RD_A2
#undef RD_B2
#undef MF_V
}

// ------------- scores: P = exp(qk^T/32 - 8), 256x256 tile, 8-phase ----------
// 1D grid 256 blocks (exactly 1 round), 512 threads. XCD x: z=x>>1, by in
// {(x&1)*4..+3}, bx 0..7. Epilogue: exp(acc/32-8), 16-lane reduce,
// lpart slot = bx*4 + (wave&3)  (32 partials/row).
__global__ __launch_bounds__(512, 2) void scores_gemm8(
    const half_t* __restrict__ qk, half_t* __restrict__ sc,
    float* __restrict__ lpart) {
  __shared__ __align__(16) half_t As[2][256 * 64];
  __shared__ __align__(16) half_t Bs[2][256 * 64];

  const int id  = blockIdx.x;
  const int x   = id & 7, j = id >> 3;
  const int bx  = j & 7;
  const int z   = x >> 1;
  const int by  = (x & 1) * 4 + (j >> 3);
  const int m0  = by * 256;
  const int n0  = bx * 256;
  const half_t* A  = qk + (size_t)z * 2048 * 2048;  // q rows (ld 2048)
  const half_t* Bm = A + 1024;                      // k rows
  half_t* C = sc + (size_t)z * 2048 * 2048;

  const int t     = threadIdx.x;
  const int lane  = t & 63;
  const int wave  = t >> 6;
  const int wr128 = (wave >> 2) * 128;
  const int wc64  = (wave & 3) * 64;
  const int lm    = lane & 15;
  const int lq    = lane >> 4;
  const int pos0  = (lq ^ (lm & 7)) * 8;
  const int pos1  = ((4 + lq) ^ (lm & 7)) * 8;
  const int t8    = t * 8;

  const int trow = t >> 3;
  const int tchk = (t & 7) ^ (trow & 7);
  const half_t* gA0 = A  + (size_t)(m0 + trow) * 2048 + tchk * 8;
  const half_t* gB0 = Bm + (size_t)(n0 + trow) * 2048 + tchk * 8;

  f32x4 acc[8][4] = {};
  half8 va[4][2], vb0[2][2], vb1[2][2];

#define ST_A(buf, h, kt) do {                                                  \
    load16_to_lds(gA0 + (size_t)((h)*128) * 2048 + (size_t)(kt) * 64,          \
                  &As[buf][(h)*128*64] + t8);                                  \
    load16_to_lds(gA0 + (size_t)((h)*128+64) * 2048 + (size_t)(kt) * 64,       \
                  &As[buf][((h)*128+64)*64] + t8);                             \
  } while (0)
#define ST_B(buf, h, kt) do {                                                  \
    load16_to_lds(gB0 + (size_t)((h)*128) * 2048 + (size_t)(kt) * 64,          \
                  &Bs[buf][(h)*128*64] + t8);                                  \
    load16_to_lds(gB0 + (size_t)((h)*128+64) * 2048 + (size_t)(kt) * 64,       \
                  &Bs[buf][((h)*128+64)*64] + t8);                             \
  } while (0)
#define RD_A(buf, mh) do {                                                     \
    _Pragma("unroll") for (int m = 0; m < 4; ++m) {                            \
      const int ar = wr128 + (mh)*64 + m * 16 + lm;                            \
      va[m][0] = *(const half8*)&As[buf][ar * 64 + pos0];                      \
      va[m][1] = *(const half8*)&As[buf][ar * 64 + pos1];                      \
    } } while (0)
#define RD_B(buf, nh, vb) do {                                                 \
    _Pragma("unroll") for (int n = 0; n < 2; ++n) {                            \
      const int br = wc64 + (nh)*32 + n * 16 + lm;                             \
      vb[n][0] = *(const half8*)&Bs[buf][br * 64 + pos0];                      \
      vb[n][1] = *(const half8*)&Bs[buf][br * 64 + pos1];                      \
    } } while (0)
#define MF_Q(mh, nh, vb) do {                                                  \
    _Pragma("unroll") for (int kk = 0; kk < 2; ++kk)                           \
    _Pragma("unroll") for (int m = 0; m < 4; ++m)                              \
    _Pragma("unroll") for (int n = 0; n < 2; ++n)                              \
      acc[(mh)*4+m][(nh)*2+n] = __builtin_amdgcn_mfma_f32_16x16x32_f16(        \
          va[m][kk], vb[n][kk], acc[(mh)*4+m][(nh)*2+n], 0, 0, 0);             \
  } while (0)

  ST_A(0, 0, 0); ST_A(0, 1, 0);
  ST_B(0, 0, 0); ST_B(0, 1, 0);
  ST_B(1, 0, 1); ST_B(1, 1, 1);
  VM4;
  BAR;

#pragma unroll 1
  for (int i = 0; i < 8; ++i) {
    const int st1 = (2 * i + 1 < 15) ? 2 * i + 1 : 15;
    const int st2 = (2 * i + 2 < 15) ? 2 * i + 2 : 15;
    const int st3 = (2 * i + 3 < 15) ? 2 * i + 3 : 15;
    // ---- P1
    RD_A(0, 0); RD_B(0, 0, vb0);
    ST_A(1, 0, st1);
    LGKM8;
    BAR; LGKM0;
    PRIO1; MF_Q(0, 0, vb0); PRIO0;
    BAR;
    // ---- P2
    RD_B(0, 1, vb1);
    ST_A(1, 1, st1);
    BAR; LGKM0;
    PRIO1; MF_Q(0, 1, vb1); PRIO0;
    BAR;
    // ---- P3
    RD_A(0, 1);
    ST_B(0, 0, st2);
    BAR; LGKM0;
    PRIO1; MF_Q(1, 0, vb0); PRIO0;
    BAR;
    // ---- P4
    ST_B(0, 1, st2);
    BAR; LGKM0;
    PRIO1; MF_Q(1, 1, vb1); PRIO0;
    VM4;
    BAR;
    // ---- P5
    RD_A(1, 0); RD_B(1, 0, vb0);
    ST_A(0, 0, st2);
    LGKM8;
    BAR; LGKM0;
    PRIO1; MF_Q(0, 0, vb0); PRIO0;
    BAR;
    // ---- P6
    RD_B(1, 1, vb1);
    ST_A(0, 1, st2);
    BAR; LGKM0;
    PRIO1; MF_Q(0, 1, vb1); PRIO0;
    BAR;
    // ---- P7
    RD_A(1, 1);
    ST_B(1, 0, st3);
    BAR; LGKM0;
    PRIO1; MF_Q(1, 0, vb0); PRIO0;
    BAR;
    // ---- P8
    ST_B(1, 1, st3);
    BAR; LGKM0;
    PRIO1; MF_Q(1, 1, vb1); PRIO0;
    VM4;
    BAR;
  }

  const float scale = 1.0f / 32.0f;
#pragma unroll
  for (int m = 0; m < 8; ++m)
#pragma unroll
    for (int r = 0; r < 4; ++r) {
      const int row = m0 + wr128 + m * 16 + lq * 4 + r;
      float s = 0.f;
#pragma unroll
      for (int n = 0; n < 4; ++n) {
        const int col = n0 + wc64 + n * 16 + lm;
        float v = __expf(acc[m][n][r] * scale - 8.0f);
        s += v;
        C[(size_t)row * 2048 + col] = (half_t)v;
      }
      s += __shfl_xor(s, 1); s += __shfl_xor(s, 2);
      s += __shfl_xor(s, 4); s += __shfl_xor(s, 8);
      if (lm == 0)
        lpart[((size_t)z * 2048 + row) * 32 + bx * 4 + (wave & 3)] = s;
    }
#undef ST_A
#undef ST_B
#undef RD_A
#undef RD_B
#undef MF_Q
}

// --------------- pv: out = (P @ V) / l, 128x128 tile, 16x16x32 ---------------
// Grid (16 q-tiles, 8 d-tiles, 4 b): same-q blocks 16 apart -> same XCD
// (P row-block stays L2-resident across its 8 d-blocks).
__global__ __launch_bounds__(256) void pv_gemm(
    const half_t* __restrict__ sc, const half_t* __restrict__ vtg,
    float* __restrict__ out, const float* __restrict__ lpart) {
  __shared__ __align__(16) half_t As[128 * 64];
  __shared__ __align__(16) half_t Bs[128 * 64];
  __shared__ float linv[128];

  const int z  = blockIdx.z;
  const int m0 = blockIdx.x * 128;
  const int n0 = blockIdx.y * 128;
  const half_t* A  = sc  + (size_t)z * 2048 * 2048;
  const half_t* Bm = vtg + (size_t)z * 2048;
  float* C = out + (size_t)z * 2048 * 1024;
  constexpr int lda = 2048, ldb = 8192, ldc = 1024, K = 2048;

  const int t    = threadIdx.x;
  const int wave = t >> 6;
  const int lane = t & 63;
  const int wm   = (wave >> 1) * 64;
  const int wn   = (wave & 1) * 64;
  const int lm   = lane & 15;
  const int lq   = lane >> 4;
  const int lswz = lm & 7;

  // Reduce 32 per-row partials to 1/l (covered by the loop's first barrier)
  if (t < 128) {
    const float4* lp = (const float4*)&lpart[((size_t)z * 2048 + m0 + t) * 32];
    float s = 0.f;
#pragma unroll
    for (int p = 0; p < 8; ++p) {
      float4 v = lp[p];
      s += v.x + v.y + v.z + v.w;
    }
    linv[t] = 1.0f / s;
  }

  const int trow = t >> 3;
  const int tchk = (t & 7) ^ (trow & 7);

  const half_t* gA0 = A  + (size_t)(m0 + trow) * lda + tchk * 8;
  const half_t* gB0 = Bm + (size_t)(n0 + trow) * ldb + tchk * 8;
  const size_t stepA = (size_t)32 * lda;
  const size_t stepB = (size_t)32 * ldb;

  half_t* lA0 = &As[t * 8];
  half_t* lB0 = &Bs[t * 8];

  f32x4 acc[4][4] = {};

  for (int k0 = 0; k0 < K; k0 += 64) {
    __syncthreads();
#pragma unroll
    for (int n = 0; n < 4; ++n) {
      load16_to_lds(gA0 + n * stepA + k0, lA0 + n * 2048);
      load16_to_lds(gB0 + n * stepB + k0, lB0 + n * 2048);
    }
    __syncthreads();

#pragma unroll
    for (int kk = 0; kk < 2; ++kk) {
      const int pos = ((kk * 4 + lq) ^ lswz) * 8;
      half8 a[4], bf[4];
#pragma unroll
      for (int i = 0; i < 4; ++i)
        a[i] = *(const half8*)&As[(wm + i * 16 + lm) * 64 + pos];
#pragma unroll
      for (int j = 0; j < 4; ++j)
        bf[j] = *(const half8*)&Bs[(wn + j * 16 + lm) * 64 + pos];
#pragma unroll
      for (int i = 0; i < 4; ++i)
#pragma unroll
        for (int j = 0; j < 4; ++j)
          acc[i][j] = __builtin_amdgcn_mfma_f32_16x16x32_f16(a[i], bf[j], acc[i][j], 0, 0, 0);
    }
  }

#pragma unroll
  for (int i = 0; i < 4; ++i)
#pragma unroll
    for (int r = 0; r < 4; ++r) {
      const int lrow = wm + i * 16 + lq * 4 + r;
      const float inv = linv[lrow];
      const int row = m0 + lrow;
#pragma unroll
      for (int j = 0; j < 4; ++j) {
        const int col = n0 + wn + j * 16 + lm;
        C[(size_t)row * ldc + col] = acc[i][j][r] * inv;
      }
    }
}

// --------------- prep: cast x + transpose weights (1 launch) -----------------
__global__ __launch_bounds__(256) void prep(
    const float* __restrict__ x, half_t* __restrict__ xh,
    const float* __restrict__ Wq, const float* __restrict__ Wk,
    const float* __restrict__ Wv, half_t* __restrict__ wt) {
  __shared__ half_t tile[32][33];
  const int b = blockIdx.x;
  const int t = threadIdx.x;
  if (b < 8192) {
    const int i = (b * 256 + t) * 4;
    const float4 v = *reinterpret_cast<const float4*>(x + i);
    half4v o;
    o.x = (half_t)v.x; o.y = (half_t)v.y; o.z = (half_t)v.z; o.w = (half_t)v.w;
    *reinterpret_cast<half4v*>(xh + i) = o;
  } else {
    int bb = b - 8192;
    const int w = bb >> 10; bb &= 1023;
    const float* in = (w == 0) ? Wq : (w == 1) ? Wk : Wv;
    half_t* o = wt + (size_t)w * 1024 * 1024;
    const int r0 = (bb >> 5) * 32, c0 = (bb & 31) * 32;
    const int tx = t & 31, ty = t >> 5;
#pragma unroll
    for (int i = 0; i < 32; i += 8)
      tile[ty + i][tx] = (half_t)in[(size_t)(r0 + ty + i) * 1024 + c0 + tx];
    __syncthreads();
#pragma unroll
    for (int i = 0; i < 32; i += 8)
      o[(size_t)(c0 + ty + i) * 1024 + r0 + tx] = tile[tx][ty + i];
  }
}

extern "C" void kernel_launch(void* const* d_in, const int* in_sizes, int n_in,
                              void* d_out, int out_size, void* d_ws, size_t ws_size,
                              hipStream_t stream) {
  constexpr int Bb = 4, S = 2048, D = 1024;
  constexpr size_t MS = (size_t)Bb * S;  // 8192 rows

  const float* x  = (const float*)d_in[0];
  const float* Wq = (const float*)d_in[1];
  const float* Wk = (const float*)d_in[2];
  const float* Wv = (const float*)d_in[3];
  float* out = (float*)d_out;

  // Workspace carve (~103 MB).
  char* p = (char*)d_ws;
  half_t* xh    = (half_t*)p; p += MS * D * 2;               // 16 MB
  half_t* wt    = (half_t*)p; p += (size_t)3 * D * D * 2;    // 6 MB  [Wq|Wk|Wv]^T
  half_t* qk    = (half_t*)p; p += MS * (size_t)(2 * D) * 2; // 32 MB [B*S, 2D]
  half_t* vtg   = (half_t*)p; p += (size_t)D * MS * 2;       // 16 MB [D, B*S]
  half_t* sc    = (half_t*)p; p += (size_t)Bb * S * S * 2;   // 32 MB P=exp(s-8)
  float*  lpart = (float*)p;  p += MS * 32 * 4;              // 1 MB partial sums

  prep<<<11264, 256, 0, stream>>>(x, xh, Wq, Wk, Wv, wt);
  qkvt_gemm8<<<256, 512, 0, stream>>>(xh, wt, qk, vtg);
  scores_gemm8<<<256, 512, 0, stream>>>(qk, sc, lpart);
  pv_gemm<<<dim3(16, 8, Bb), 256, 0, stream>>>(sc, vtg, out, lpart);
}

// Round 5
// 219.272 us; speedup vs baseline: 1.1342x; 1.0195x over previous
//
#include <hip/hip_runtime.h>
#include <hip/hip_bf16.h>

// SelfAttention: B=4, S=2048, D=1024, fp32 in/out.
// Round 13: pv ported to the verified VT-style 8-phase 128x256 template
// (the exact loop body that passed inside qkvt_gemm8 since R12).
//  - qkvt_gemm8: unchanged R12 (61.3us measured, 840 TF = template ceiling).
//  - scores_gemm8: unchanged R10/R12.
//  - pv_gemm8: 128x256 tile, K=2048 (16 iters), grid 256 = 1 clean round,
//    8 waves x 64x64 wave tile, staging P3/P4/P7/P8 + VM6 counted drain,
//    XCD map: x -> z=x>>1, q-group; consecutive j share A-panel.
//  - prep: unchanged.
// 4 launches: prep, qkvt8, scores8, pv8.

typedef _Float16 half_t;
typedef _Float16 half8 __attribute__((ext_vector_type(8)));
typedef _Float16 half4v __attribute__((ext_vector_type(4)));
typedef float f32x4 __attribute__((ext_vector_type(4)));

__device__ __forceinline__ void load16_to_lds(const half_t* g, half_t* l) {
  __builtin_amdgcn_global_load_lds(
      (const __attribute__((address_space(1))) void*)g,
      (__attribute__((address_space(3))) void*)l, 16, 0, 0);
}

#define LGKM0 asm volatile("s_waitcnt lgkmcnt(0)" ::: "memory")
#define LGKM8 asm volatile("s_waitcnt lgkmcnt(8)" ::: "memory")
#define VM0   asm volatile("s_waitcnt vmcnt(0)" ::: "memory")
#define VM4   asm volatile("s_waitcnt vmcnt(4)" ::: "memory")
#define VM6   asm volatile("s_waitcnt vmcnt(6)" ::: "memory")
#define BAR   __builtin_amdgcn_s_barrier()
#define PRIO1 __builtin_amdgcn_s_setprio(1)
#define PRIO0 __builtin_amdgcn_s_setprio(0)

// --------- qkvt: QK 256x256 tile + VT 128x256 half-tile per block ----------
// Grid 256 x 512 threads. x = b&7 (XCD), j = b>>3.
// QK: qk[8192,2048] = x @ [Wq|Wk]^T; m0=(x*4+(j&3))*256, n0=(j>>2)*256.
// VT: vtg[1024,8192] = Wv^T @ x^T;  m0v=(j>>2)*128, n0v=(x*4+(j&3))*256.
__global__ __launch_bounds__(512, 2) void qkvt_gemm8(
    const half_t* __restrict__ xh, const half_t* __restrict__ wt,
    half_t* __restrict__ qk, half_t* __restrict__ vtg) {
  __shared__ __align__(16) half_t As[2][256 * 64];
  __shared__ __align__(16) half_t Bs[2][256 * 64];

  const int b = blockIdx.x;
  const int x = b & 7, j = b >> 3;
  const int m0 = (x * 4 + (j & 3)) * 256;
  const int n0 = (j >> 2) * 256;

  const int t     = threadIdx.x;
  const int lane  = t & 63;
  const int wave  = t >> 6;
  const int wr128 = (wave >> 2) * 128;
  const int wc64  = (wave & 3) * 64;
  const int lm    = lane & 15;
  const int lq    = lane >> 4;
  const int pos0  = (lq ^ (lm & 7)) * 8;
  const int pos1  = ((4 + lq) ^ (lm & 7)) * 8;
  const int t8    = t * 8;

  const int trow = t >> 3;
  const int tchk = (t & 7) ^ (trow & 7);
  const half_t* gA0 = xh + (size_t)(m0 + trow) * 1024 + tchk * 8;
  const half_t* gB0 = wt + (size_t)(n0 + trow) * 1024 + tchk * 8;

  f32x4 acc[8][4] = {};
  half8 va[4][2], vb0[2][2], vb1[2][2];

#define ST_A(buf, h, kt) do {                                                  \
    load16_to_lds(gA0 + (size_t)((h)*128) * 1024 + (size_t)(kt) * 64,          \
                  &As[buf][(h)*128*64] + t8);                                  \
    load16_to_lds(gA0 + (size_t)((h)*128+64) * 1024 + (size_t)(kt) * 64,       \
                  &As[buf][((h)*128+64)*64] + t8);                             \
  } while (0)
#define ST_B(buf, h, kt) do {                                                  \
    load16_to_lds(gB0 + (size_t)((h)*128) * 1024 + (size_t)(kt) * 64,          \
                  &Bs[buf][(h)*128*64] + t8);                                  \
    load16_to_lds(gB0 + (size_t)((h)*128+64) * 1024 + (size_t)(kt) * 64,       \
                  &Bs[buf][((h)*128+64)*64] + t8);                             \
  } while (0)
#define RD_A(buf, mh) do {                                                     \
    _Pragma("unroll") for (int m = 0; m < 4; ++m) {                            \
      const int ar = wr128 + (mh)*64 + m * 16 + lm;                            \
      va[m][0] = *(const half8*)&As[buf][ar * 64 + pos0];                      \
      va[m][1] = *(const half8*)&As[buf][ar * 64 + pos1];                      \
    } } while (0)
#define RD_B(buf, nh, vb) do {                                                 \
    _Pragma("unroll") for (int n = 0; n < 2; ++n) {                            \
      const int br = wc64 + (nh)*32 + n * 16 + lm;                             \
      vb[n][0] = *(const half8*)&Bs[buf][br * 64 + pos0];                      \
      vb[n][1] = *(const half8*)&Bs[buf][br * 64 + pos1];                      \
    } } while (0)
#define MF_Q(mh, nh, vb) do {                                                  \
    _Pragma("unroll") for (int kk = 0; kk < 2; ++kk)                           \
    _Pragma("unroll") for (int m = 0; m < 4; ++m)                              \
    _Pragma("unroll") for (int n = 0; n < 2; ++n)                              \
      acc[(mh)*4+m][(nh)*2+n] = __builtin_amdgcn_mfma_f32_16x16x32_f16(        \
          va[m][kk], vb[n][kk], acc[(mh)*4+m][(nh)*2+n], 0, 0, 0);             \
  } while (0)

  ST_A(0, 0, 0); ST_A(0, 1, 0);
  ST_B(0, 0, 0); ST_B(0, 1, 0);
  ST_B(1, 0, 1); ST_B(1, 1, 1);
  VM4;
  BAR;

#pragma unroll 1
  for (int i = 0; i < 8; ++i) {
    const int st1 = (2 * i + 1 < 15) ? 2 * i + 1 : 15;
    const int st2 = (2 * i + 2 < 15) ? 2 * i + 2 : 15;
    const int st3 = (2 * i + 3 < 15) ? 2 * i + 3 : 15;
    // ---- P1
    RD_A(0, 0); RD_B(0, 0, vb0);
    ST_A(1, 0, st1);
    LGKM8;
    BAR; LGKM0;
    PRIO1; MF_Q(0, 0, vb0); PRIO0;
    BAR;
    // ---- P2
    RD_B(0, 1, vb1);
    ST_A(1, 1, st1);
    BAR; LGKM0;
    PRIO1; MF_Q(0, 1, vb1); PRIO0;
    BAR;
    // ---- P3
    RD_A(0, 1);
    ST_B(0, 0, st2);
    BAR; LGKM0;
    PRIO1; MF_Q(1, 0, vb0); PRIO0;
    BAR;
    // ---- P4
    ST_B(0, 1, st2);
    BAR; LGKM0;
    PRIO1; MF_Q(1, 1, vb1); PRIO0;
    VM4;
    BAR;
    // ---- P5
    RD_A(1, 0); RD_B(1, 0, vb0);
    ST_A(0, 0, st2);
    LGKM8;
    BAR; LGKM0;
    PRIO1; MF_Q(0, 0, vb0); PRIO0;
    BAR;
    // ---- P6
    RD_B(1, 1, vb1);
    ST_A(0, 1, st2);
    BAR; LGKM0;
    PRIO1; MF_Q(0, 1, vb1); PRIO0;
    BAR;
    // ---- P7
    RD_A(1, 1);
    ST_B(1, 0, st3);
    BAR; LGKM0;
    PRIO1; MF_Q(1, 0, vb0); PRIO0;
    BAR;
    // ---- P8
    ST_B(1, 1, st3);
    BAR; LGKM0;
    PRIO1; MF_Q(1, 1, vb1); PRIO0;
    VM4;
    BAR;
  }

  // 16x16 C/D: col=lane&15, row=(lane>>4)*4+reg  [m89/m91]
#pragma unroll
  for (int m = 0; m < 8; ++m)
#pragma unroll
    for (int n = 0; n < 4; ++n) {
      const int col = n0 + wc64 + n * 16 + lm;
#pragma unroll
      for (int r = 0; r < 4; ++r) {
        const int row = m0 + wr128 + m * 16 + lq * 4 + r;
        qk[(size_t)row * 2048 + col] = (half_t)acc[m][n][r];
      }
    }
#undef ST_A
#undef ST_B
#undef RD_A
#undef RD_B
#undef MF_Q

  // ======================= VT half-tile: 128x256, K=1024 ====================
  const int m0v = (j >> 2) * 128;
  const int n0v = (x * 4 + (j & 3)) * 256;
  const int wmv = (wave >> 2) * 64;   // 2 M-waves
  const int wnv = (wave & 3) * 64;    // 4 N-waves

  const half_t* gA2 = wt + (size_t)2 * 1024 * 1024 +
                      (size_t)(m0v + trow) * 1024 + tchk * 8;
  const half_t* gB2 = xh + (size_t)(n0v + trow) * 1024 + tchk * 8;

  f32x4 acc2[4][4] = {};

#define ST_A2(buf, kt) do {                                                    \
    load16_to_lds(gA2 + (size_t)(kt) * 64, &As[buf][0] + t8);                  \
    load16_to_lds(gA2 + (size_t)64 * 1024 + (size_t)(kt) * 64,                 \
                  &As[buf][64*64] + t8);                                       \
  } while (0)
#define ST_B2(buf, h, kt) do {                                                 \
    load16_to_lds(gB2 + (size_t)((h)*128) * 1024 + (size_t)(kt) * 64,          \
                  &Bs[buf][(h)*128*64] + t8);                                  \
    load16_to_lds(gB2 + (size_t)((h)*128+64) * 1024 + (size_t)(kt) * 64,       \
                  &Bs[buf][((h)*128+64)*64] + t8);                             \
  } while (0)
#define RD_A2(buf, mh) do {                                                    \
    _Pragma("unroll") for (int m = 0; m < 2; ++m) {                            \
      const int ar = wmv + (mh)*32 + m * 16 + lm;                              \
      va[(mh)*2+m][0] = *(const half8*)&As[buf][ar * 64 + pos0];               \
      va[(mh)*2+m][1] = *(const half8*)&As[buf][ar * 64 + pos1];               \
    } } while (0)
#define RD_B2(buf, nh, vb) do {                                                \
    _Pragma("unroll") for (int n = 0; n < 2; ++n) {                            \
      const int br = wnv + (nh)*32 + n * 16 + lm;                              \
      vb[n][0] = *(const half8*)&Bs[buf][br * 64 + pos0];                      \
      vb[n][1] = *(const half8*)&Bs[buf][br * 64 + pos1];                      \
    } } while (0)
#define MF_V(mh, nh, vb) do {                                                  \
    _Pragma("unroll") for (int kk = 0; kk < 2; ++kk)                           \
    _Pragma("unroll") for (int m = 0; m < 2; ++m)                              \
    _Pragma("unroll") for (int n = 0; n < 2; ++n)                              \
      acc2[(mh)*2+m][(nh)*2+n] = __builtin_amdgcn_mfma_f32_16x16x32_f16(       \
          va[(mh)*2+m][kk], vb[n][kk], acc2[(mh)*2+m][(nh)*2+n], 0, 0, 0);     \
  } while (0)

  // Drain QK's in-flight staged loads + epilogue stores before LDS reuse.
  VM0;
  ST_B2(0, 0, 0); ST_B2(0, 1, 0); ST_A2(0, 0);   // b0 <- K-tile 0
  ST_B2(1, 0, 1); ST_B2(1, 1, 1); ST_A2(1, 1);   // b1 <- K-tile 1
  VM6;
  BAR;

#pragma unroll 1
  for (int i = 0; i < 8; ++i) {
    const int t2 = (2 * i + 2 < 15) ? 2 * i + 2 : 15;
    const int t3 = (2 * i + 3 < 15) ? 2 * i + 3 : 15;
    // ---- P1
    RD_A2(0, 0); RD_B2(0, 0, vb0);
    BAR; LGKM0;
    PRIO1; MF_V(0, 0, vb0); PRIO0;
    BAR;
    // ---- P2
    RD_B2(0, 1, vb1);
    BAR; LGKM0;
    PRIO1; MF_V(0, 1, vb1); PRIO0;
    BAR;
    // ---- P3  (B(b0) reads done after P2-bar)
    RD_A2(0, 1);
    ST_B2(0, 0, t2);
    BAR; LGKM0;
    PRIO1; MF_V(1, 0, vb0); PRIO0;
    BAR;
    // ---- P4  (A(b0) reads done after P3-bar)
    ST_B2(0, 1, t2); ST_A2(0, t2);
    BAR; LGKM0;
    PRIO1; MF_V(1, 1, vb1); PRIO0;
    VM6;              // drains the 6 b1 loads (issued prev P7/P8 or prologue)
    BAR;
    // ---- P5
    RD_A2(1, 0); RD_B2(1, 0, vb0);
    BAR; LGKM0;
    PRIO1; MF_V(0, 0, vb0); PRIO0;
    BAR;
    // ---- P6
    RD_B2(1, 1, vb1);
    BAR; LGKM0;
    PRIO1; MF_V(0, 1, vb1); PRIO0;
    BAR;
    // ---- P7  (B(b1) reads done after P6-bar)
    RD_A2(1, 1);
    ST_B2(1, 0, t3);
    BAR; LGKM0;
    PRIO1; MF_V(1, 0, vb0); PRIO0;
    BAR;
    // ---- P8  (A(b1) reads done after P7-bar)
    ST_B2(1, 1, t3); ST_A2(1, t3);
    BAR; LGKM0;
    PRIO1; MF_V(1, 1, vb1); PRIO0;
    VM6;              // drains the 6 b0 loads (issued P3/P4)
    BAR;
  }

#pragma unroll
  for (int m = 0; m < 4; ++m)
#pragma unroll
    for (int n = 0; n < 4; ++n) {
      const int col = n0v + wnv + n * 16 + lm;
#pragma unroll
      for (int r = 0; r < 4; ++r) {
        const int row = m0v + wmv + m * 16 + lq * 4 + r;
        vtg[(size_t)row * 8192 + col] = (half_t)acc2[m][n][r];
      }
    }
#undef ST_A2
#undef ST_B2
#undef RD_A2
#undef RD_B2
#undef MF_V
}

// ------------- scores: P = exp(qk^T/32 - 8), 256x256 tile, 8-phase ----------
// 1D grid 256 blocks (exactly 1 round), 512 threads. XCD x: z=x>>1, by in
// {(x&1)*4..+3}, bx 0..7. Epilogue: exp(acc/32-8), 16-lane reduce,
// lpart slot = bx*4 + (wave&3)  (32 partials/row).
__global__ __launch_bounds__(512, 2) void scores_gemm8(
    const half_t* __restrict__ qk, half_t* __restrict__ sc,
    float* __restrict__ lpart) {
  __shared__ __align__(16) half_t As[2][256 * 64];
  __shared__ __align__(16) half_t Bs[2][256 * 64];

  const int id  = blockIdx.x;
  const int x   = id & 7, j = id >> 3;
  const int bx  = j & 7;
  const int z   = x >> 1;
  const int by  = (x & 1) * 4 + (j >> 3);
  const int m0  = by * 256;
  const int n0  = bx * 256;
  const half_t* A  = qk + (size_t)z * 2048 * 2048;  // q rows (ld 2048)
  const half_t* Bm = A + 1024;                      // k rows
  half_t* C = sc + (size_t)z * 2048 * 2048;

  const int t     = threadIdx.x;
  const int lane  = t & 63;
  const int wave  = t >> 6;
  const int wr128 = (wave >> 2) * 128;
  const int wc64  = (wave & 3) * 64;
  const int lm    = lane & 15;
  const int lq    = lane >> 4;
  const int pos0  = (lq ^ (lm & 7)) * 8;
  const int pos1  = ((4 + lq) ^ (lm & 7)) * 8;
  const int t8    = t * 8;

  const int trow = t >> 3;
  const int tchk = (t & 7) ^ (trow & 7);
  const half_t* gA0 = A  + (size_t)(m0 + trow) * 2048 + tchk * 8;
  const half_t* gB0 = Bm + (size_t)(n0 + trow) * 2048 + tchk * 8;

  f32x4 acc[8][4] = {};
  half8 va[4][2], vb0[2][2], vb1[2][2];

#define ST_A(buf, h, kt) do {                                                  \
    load16_to_lds(gA0 + (size_t)((h)*128) * 2048 + (size_t)(kt) * 64,          \
                  &As[buf][(h)*128*64] + t8);                                  \
    load16_to_lds(gA0 + (size_t)((h)*128+64) * 2048 + (size_t)(kt) * 64,       \
                  &As[buf][((h)*128+64)*64] + t8);                             \
  } while (0)
#define ST_B(buf, h, kt) do {                                                  \
    load16_to_lds(gB0 + (size_t)((h)*128) * 2048 + (size_t)(kt) * 64,          \
                  &Bs[buf][(h)*128*64] + t8);                                  \
    load16_to_lds(gB0 + (size_t)((h)*128+64) * 2048 + (size_t)(kt) * 64,       \
                  &Bs[buf][((h)*128+64)*64] + t8);                             \
  } while (0)
#define RD_A(buf, mh) do {                                                     \
    _Pragma("unroll") for (int m = 0; m < 4; ++m) {                            \
      const int ar = wr128 + (mh)*64 + m * 16 + lm;                            \
      va[m][0] = *(const half8*)&As[buf][ar * 64 + pos0];                      \
      va[m][1] = *(const half8*)&As[buf][ar * 64 + pos1];                      \
    } } while (0)
#define RD_B(buf, nh, vb) do {                                                 \
    _Pragma("unroll") for (int n = 0; n < 2; ++n) {                            \
      const int br = wc64 + (nh)*32 + n * 16 + lm;                             \
      vb[n][0] = *(const half8*)&Bs[buf][br * 64 + pos0];                      \
      vb[n][1] = *(const half8*)&Bs[buf][br * 64 + pos1];                      \
    } } while (0)
#define MF_Q(mh, nh, vb) do {                                                  \
    _Pragma("unroll") for (int kk = 0; kk < 2; ++kk)                           \
    _Pragma("unroll") for (int m = 0; m < 4; ++m)                              \
    _Pragma("unroll") for (int n = 0; n < 2; ++n)                              \
      acc[(mh)*4+m][(nh)*2+n] = __builtin_amdgcn_mfma_f32_16x16x32_f16(        \
          va[m][kk], vb[n][kk], acc[(mh)*4+m][(nh)*2+n], 0, 0, 0);             \
  } while (0)

  ST_A(0, 0, 0); ST_A(0, 1, 0);
  ST_B(0, 0, 0); ST_B(0, 1, 0);
  ST_B(1, 0, 1); ST_B(1, 1, 1);
  VM4;
  BAR;

#pragma unroll 1
  for (int i = 0; i < 8; ++i) {
    const int st1 = (2 * i + 1 < 15) ? 2 * i + 1 : 15;
    const int st2 = (2 * i + 2 < 15) ? 2 * i + 2 : 15;
    const int st3 = (2 * i + 3 < 15) ? 2 * i + 3 : 15;
    // ---- P1
    RD_A(0, 0); RD_B(0, 0, vb0);
    ST_A(1, 0, st1);
    LGKM8;
    BAR; LGKM0;
    PRIO1; MF_Q(0, 0, vb0); PRIO0;
    BAR;
    // ---- P2
    RD_B(0, 1, vb1);
    ST_A(1, 1, st1);
    BAR; LGKM0;
    PRIO1; MF_Q(0, 1, vb1); PRIO0;
    BAR;
    // ---- P3
    RD_A(0, 1);
    ST_B(0, 0, st2);
    BAR; LGKM0;
    PRIO1; MF_Q(1, 0, vb0); PRIO0;
    BAR;
    // ---- P4
    ST_B(0, 1, st2);
    BAR; LGKM0;
    PRIO1; MF_Q(1, 1, vb1); PRIO0;
    VM4;
    BAR;
    // ---- P5
    RD_A(1, 0); RD_B(1, 0, vb0);
    ST_A(0, 0, st2);
    LGKM8;
    BAR; LGKM0;
    PRIO1; MF_Q(0, 0, vb0); PRIO0;
    BAR;
    // ---- P6
    RD_B(1, 1, vb1);
    ST_A(0, 1, st2);
    BAR; LGKM0;
    PRIO1; MF_Q(0, 1, vb1); PRIO0;
    BAR;
    // ---- P7
    RD_A(1, 1);
    ST_B(1, 0, st3);
    BAR; LGKM0;
    PRIO1; MF_Q(1, 0, vb0); PRIO0;
    BAR;
    // ---- P8
    ST_B(1, 1, st3);
    BAR; LGKM0;
    PRIO1; MF_Q(1, 1, vb1); PRIO0;
    VM4;
    BAR;
  }

  const float scale = 1.0f / 32.0f;
#pragma unroll
  for (int m = 0; m < 8; ++m)
#pragma unroll
    for (int r = 0; r < 4; ++r) {
      const int row = m0 + wr128 + m * 16 + lq * 4 + r;
      float s = 0.f;
#pragma unroll
      for (int n = 0; n < 4; ++n) {
        const int col = n0 + wc64 + n * 16 + lm;
        float v = __expf(acc[m][n][r] * scale - 8.0f);
        s += v;
        C[(size_t)row * 2048 + col] = (half_t)v;
      }
      s += __shfl_xor(s, 1); s += __shfl_xor(s, 2);
      s += __shfl_xor(s, 4); s += __shfl_xor(s, 8);
      if (lm == 0)
        lpart[((size_t)z * 2048 + row) * 32 + bx * 4 + (wave & 3)] = s;
    }
#undef ST_A
#undef ST_B
#undef RD_A
#undef RD_B
#undef MF_Q
}

// ---------- pv: out = (P @ V) / l, 128x256 tile, 8-phase, K=2048 ------------
// Grid 256 x 512 threads (1 clean round). id: x=id&7 (XCD), j=id>>3 (0..31).
// z = x>>1; q-tile = (x&1)*8 + (j>>2) (16 per z); d-tile = j&3 (4 of 256).
// Consecutive j share the A-panel (P rows); B d-slab (1MB) L2-reused 8x.
// Same verified VT loop body (strides: A ld 2048, B ld 8192), 16 iters.
__global__ __launch_bounds__(512, 2) void pv_gemm8(
    const half_t* __restrict__ sc, const half_t* __restrict__ vtg,
    float* __restrict__ out, const float* __restrict__ lpart) {
  __shared__ __align__(16) half_t As[2][128 * 64];
  __shared__ __align__(16) half_t Bs[2][256 * 64];
  __shared__ float linv[128];

  const int id = blockIdx.x;
  const int x  = id & 7, j = id >> 3;
  const int z  = x >> 1;
  const int m0 = ((x & 1) * 8 + (j >> 2)) * 128;   // P row-tile (of 2048)
  const int n0 = (j & 3) * 256;                    // d-tile (of 1024)
  const half_t* A  = sc  + (size_t)z * 2048 * 2048;  // P rows, ld 2048
  const half_t* Bm = vtg + (size_t)z * 2048;         // V^T rows (d), ld 8192
  float* C = out + (size_t)z * 2048 * 1024;

  const int t    = threadIdx.x;
  const int lane = t & 63;
  const int wave = t >> 6;
  const int wmv  = (wave >> 2) * 64;   // 2 M-wave groups (128 rows)
  const int wnv  = (wave & 3) * 64;    // 4 N-wave groups (256 cols)
  const int lm   = lane & 15;
  const int lq   = lane >> 4;
  const int pos0 = (lq ^ (lm & 7)) * 8;
  const int pos1 = ((4 + lq) ^ (lm & 7)) * 8;
  const int t8   = t * 8;

  // Reduce 32 per-row partials to 1/l (ready before epilogue: loop barriers)
  if (t < 128) {
    const float4* lp = (const float4*)&lpart[((size_t)z * 2048 + m0 + t) * 32];
    float s = 0.f;
#pragma unroll
    for (int p = 0; p < 8; ++p) {
      float4 v = lp[p];
      s += v.x + v.y + v.z + v.w;
    }
    linv[t] = 1.0f / s;
  }

  const int trow = t >> 3;
  const int tchk = (t & 7) ^ (trow & 7);
  const half_t* gA2 = A  + (size_t)(m0 + trow) * 2048 + tchk * 8;
  const half_t* gB2 = Bm + (size_t)(n0 + trow) * 8192 + tchk * 8;

  f32x4 acc2[4][4] = {};
  half8 va[4][2], vb0[2][2], vb1[2][2];

#define ST_A2(buf, kt) do {                                                    \
    load16_to_lds(gA2 + (size_t)(kt) * 64, &As[buf][0] + t8);                  \
    load16_to_lds(gA2 + (size_t)64 * 2048 + (size_t)(kt) * 64,                 \
                  &As[buf][64*64] + t8);                                       \
  } while (0)
#define ST_B2(buf, h, kt) do {                                                 \
    load16_to_lds(gB2 + (size_t)((h)*128) * 8192 + (size_t)(kt) * 64,          \
                  &Bs[buf][(h)*128*64] + t8);                                  \
    load16_to_lds(gB2 + (size_t)((h)*128+64) * 8192 + (size_t)(kt) * 64,       \
                  &Bs[buf][((h)*128+64)*64] + t8);                             \
  } while (0)
#define RD_A2(buf, mh) do {                                                    \
    _Pragma("unroll") for (int m = 0; m < 2; ++m) {                            \
      const int ar = wmv + (mh)*32 + m * 16 + lm;                              \
      va[(mh)*2+m][0] = *(const half8*)&As[buf][ar * 64 + pos0];               \
      va[(mh)*2+m][1] = *(const half8*)&As[buf][ar * 64 + pos1];               \
    } } while (0)
#define RD_B2(buf, nh, vb) do {                                                \
    _Pragma("unroll") for (int n = 0; n < 2; ++n) {                            \
      const int br = wnv + (nh)*32 + n * 16 + lm;                              \
      vb[n][0] = *(const half8*)&Bs[buf][br * 64 + pos0];                      \
      vb[n][1] = *(const half8*)&Bs[buf][br * 64 + pos1];                      \
    } } while (0)
#define MF_V(mh, nh, vb) do {                                                  \
    _Pragma("unroll") for (int kk = 0; kk < 2; ++kk)                           \
    _Pragma("unroll") for (int m = 0; m < 2; ++m)                              \
    _Pragma("unroll") for (int n = 0; n < 2; ++n)                              \
      acc2[(mh)*2+m][(nh)*2+n] = __builtin_amdgcn_mfma_f32_16x16x32_f16(       \
          va[(mh)*2+m][kk], vb[n][kk], acc2[(mh)*2+m][(nh)*2+n], 0, 0, 0);     \
  } while (0)

  ST_B2(0, 0, 0); ST_B2(0, 1, 0); ST_A2(0, 0);   // b0 <- K-tile 0
  ST_B2(1, 0, 1); ST_B2(1, 1, 1); ST_A2(1, 1);   // b1 <- K-tile 1
  VM6;
  BAR;

#pragma unroll 1
  for (int i = 0; i < 16; ++i) {
    const int t2 = (2 * i + 2 < 31) ? 2 * i + 2 : 31;
    const int t3 = (2 * i + 3 < 31) ? 2 * i + 3 : 31;
    // ---- P1
    RD_A2(0, 0); RD_B2(0, 0, vb0);
    BAR; LGKM0;
    PRIO1; MF_V(0, 0, vb0); PRIO0;
    BAR;
    // ---- P2
    RD_B2(0, 1, vb1);
    BAR; LGKM0;
    PRIO1; MF_V(0, 1, vb1); PRIO0;
    BAR;
    // ---- P3  (B(b0) reads done after P2-bar)
    RD_A2(0, 1);
    ST_B2(0, 0, t2);
    BAR; LGKM0;
    PRIO1; MF_V(1, 0, vb0); PRIO0;
    BAR;
    // ---- P4  (A(b0) reads done after P3-bar)
    ST_B2(0, 1, t2); ST_A2(0, t2);
    BAR; LGKM0;
    PRIO1; MF_V(1, 1, vb1); PRIO0;
    VM6;              // drains the 6 b1 loads (issued prev P7/P8 or prologue)
    BAR;
    // ---- P5
    RD_A2(1, 0); RD_B2(1, 0, vb0);
    BAR; LGKM0;
    PRIO1; MF_V(0, 0, vb0); PRIO0;
    BAR;
    // ---- P6
    RD_B2(1, 1, vb1);
    BAR; LGKM0;
    PRIO1; MF_V(0, 1, vb1); PRIO0;
    BAR;
    // ---- P7  (B(b1) reads done after P6-bar)
    RD_A2(1, 1);
    ST_B2(1, 0, t3);
    BAR; LGKM0;
    PRIO1; MF_V(1, 0, vb0); PRIO0;
    BAR;
    // ---- P8  (A(b1) reads done after P7-bar)
    ST_B2(1, 1, t3); ST_A2(1, t3);
    BAR; LGKM0;
    PRIO1; MF_V(1, 1, vb1); PRIO0;
    VM6;              // drains the 6 b0 loads (issued P3/P4)
    BAR;
  }

#pragma unroll
  for (int m = 0; m < 4; ++m)
#pragma unroll
    for (int r = 0; r < 4; ++r) {
      const int lrow = wmv + m * 16 + lq * 4 + r;
      const float inv = linv[lrow];
      const int row = m0 + lrow;
#pragma unroll
      for (int n = 0; n < 4; ++n) {
        const int col = n0 + wnv + n * 16 + lm;
        C[(size_t)row * 1024 + col] = acc2[m][n][r] * inv;
      }
    }
#undef ST_A2
#undef ST_B2
#undef RD_A2
#undef RD_B2
#undef MF_V
}

// --------------- prep: cast x + transpose weights (1 launch) -----------------
__global__ __launch_bounds__(256) void prep(
    const float* __restrict__ x, half_t* __restrict__ xh,
    const float* __restrict__ Wq, const float* __restrict__ Wk,
    const float* __restrict__ Wv, half_t* __restrict__ wt) {
  __shared__ half_t tile[32][33];
  const int b = blockIdx.x;
  const int t = threadIdx.x;
  if (b < 8192) {
    const int i = (b * 256 + t) * 4;
    const float4 v = *reinterpret_cast<const float4*>(x + i);
    half4v o;
    o.x = (half_t)v.x; o.y = (half_t)v.y; o.z = (half_t)v.z; o.w = (half_t)v.w;
    *reinterpret_cast<half4v*>(xh + i) = o;
  } else {
    int bb = b - 8192;
    const int w = bb >> 10; bb &= 1023;
    const float* in = (w == 0) ? Wq : (w == 1) ? Wk : Wv;
    half_t* o = wt + (size_t)w * 1024 * 1024;
    const int r0 = (bb >> 5) * 32, c0 = (bb & 31) * 32;
    const int tx = t & 31, ty = t >> 5;
#pragma unroll
    for (int i = 0; i < 32; i += 8)
      tile[ty + i][tx] = (half_t)in[(size_t)(r0 + ty + i) * 1024 + c0 + tx];
    __syncthreads();
#pragma unroll
    for (int i = 0; i < 32; i += 8)
      o[(size_t)(c0 + ty + i) * 1024 + r0 + tx] = tile[tx][ty + i];
  }
}

extern "C" void kernel_launch(void* const* d_in, const int* in_sizes, int n_in,
                              void* d_out, int out_size, void* d_ws, size_t ws_size,
                              hipStream_t stream) {
  constexpr int Bb = 4, S = 2048, D = 1024;
  constexpr size_t MS = (size_t)Bb * S;  // 8192 rows

  const float* x  = (const float*)d_in[0];
  const float* Wq = (const float*)d_in[1];
  const float* Wk = (const float*)d_in[2];
  const float* Wv = (const float*)d_in[3];
  float* out = (float*)d_out;

  // Workspace carve (~103 MB).
  char* p = (char*)d_ws;
  half_t* xh    = (half_t*)p; p += MS * D * 2;               // 16 MB
  half_t* wt    = (half_t*)p; p += (size_t)3 * D * D * 2;    // 6 MB  [Wq|Wk|Wv]^T
  half_t* qk    = (half_t*)p; p += MS * (size_t)(2 * D) * 2; // 32 MB [B*S, 2D]
  half_t* vtg   = (half_t*)p; p += (size_t)D * MS * 2;       // 16 MB [D, B*S]
  half_t* sc    = (half_t*)p; p += (size_t)Bb * S * S * 2;   // 32 MB P=exp(s-8)
  float*  lpart = (float*)p;  p += MS * 32 * 4;              // 1 MB partial sums

  prep<<<11264, 256, 0, stream>>>(x, xh, Wq, Wk, Wv, wt);
  qkvt_gemm8<<<256, 512, 0, stream>>>(xh, wt, qk, vtg);
  scores_gemm8<<<256, 512, 0, stream>>>(qk, sc, lpart);
  pv_gemm8<<<256, 512, 0, stream>>>(sc, vtg, out, lpart);
}